// Round 1
// baseline (585.640 us; speedup 1.0000x reference)
//
#include <hip/hip_runtime.h>

#define LL 2048
#define CC 64
#define BB 8
#define HH 4
#define GG 4

// ---------------------------------------------------------------------------
// Kernel 1: GroupNorm stats. One block per (b,g). Group channels are
// contiguous -> one contiguous 16*2048-float segment per block.
// ---------------------------------------------------------------------------
__global__ __launch_bounds__(256) void k_gnstats(const float* __restrict__ x,
                                                 float* __restrict__ stats) {
    int bg = blockIdx.x;  // 0..31
    const float4* p = (const float4*)(x + (size_t)bg * (16 * LL));
    float s1 = 0.f, s2 = 0.f;
    for (int i = threadIdx.x; i < 8192; i += 256) {
        float4 v = p[i];
        s1 += v.x + v.y + v.z + v.w;
        s2 += v.x * v.x + v.y * v.y + v.z * v.z + v.w * v.w;
    }
#pragma unroll
    for (int off = 32; off > 0; off >>= 1) {
        s1 += __shfl_down(s1, off, 64);
        s2 += __shfl_down(s2, off, 64);
    }
    __shared__ float r1[4], r2[4];
    int lane = threadIdx.x & 63, wv = threadIdx.x >> 6;
    if (lane == 0) { r1[wv] = s1; r2[wv] = s2; }
    __syncthreads();
    if (threadIdx.x == 0) {
        float sa = r1[0] + r1[1] + r1[2] + r1[3];
        float sb = r2[0] + r2[1] + r2[2] + r2[3];
        float mean = sa * (1.0f / 32768.0f);
        float var = sb * (1.0f / 32768.0f) - mean * mean;
        stats[bg * 2]     = mean;
        stats[bg * 2 + 1] = rsqrtf(var + 1e-5f);
    }
}

// ---------------------------------------------------------------------------
// Kernel 2: QKV conv1x1 with GroupNorm fused into the A-tile load.
// Tile: 64 o  x 64 l, K=64. Scale 0.5 folded into q and k outputs.
// grid (32 l-tiles, 3 o-tiles, 8 b), block 256.
// ---------------------------------------------------------------------------
__global__ __launch_bounds__(256) void k_qkv(const float* __restrict__ x,
                                             const float* __restrict__ gnw,
                                             const float* __restrict__ gnb,
                                             const float* __restrict__ qw,
                                             const float* __restrict__ qb,
                                             const float* __restrict__ stats,
                                             float* __restrict__ qkv) {
    int lt = blockIdx.x;   // 0..31
    int ot = blockIdx.y;   // 0..2
    int b  = blockIdx.z;   // 0..7
    int tid = threadIdx.x;
    int l0 = lt * 64;
    __shared__ float xs[64][64];
    __shared__ float wsh[64][64];
#pragma unroll
    for (int k = 0; k < 4; k++) {
        int chunk = tid + k * 256;        // 0..1023
        int c = chunk >> 4, l4 = chunk & 15;
        float4 v = *(const float4*)(x + ((size_t)b * CC + c) * LL + l0 + l4 * 4);
        int g = c >> 4;
        float mean = stats[(b * GG + g) * 2];
        float rstd = stats[(b * GG + g) * 2 + 1];
        float wgt = gnw[c] * rstd;
        float bia = gnb[c] - mean * wgt;
        float4 o;
        o.x = v.x * wgt + bia; o.y = v.y * wgt + bia;
        o.z = v.z * wgt + bia; o.w = v.w * wgt + bia;
        *(float4*)&xs[c][l4 * 4] = o;
        // weight tile: row o_=chunk>>4, cols c4*4..c4*4+3
        *(float4*)&wsh[c][l4 * 4] =
            *(const float4*)(qw + ((size_t)(ot * 64 + c)) * CC + l4 * 4);
    }
    __syncthreads();
    int ll = tid & 63, og = tid >> 6;   // og uniform per wave
    float acc[16];
#pragma unroll
    for (int i = 0; i < 16; i++) acc[i] = 0.f;
    for (int c = 0; c < 64; c += 4) {
        float x0 = xs[c][ll], x1 = xs[c + 1][ll];
        float x2 = xs[c + 2][ll], x3 = xs[c + 3][ll];
#pragma unroll
        for (int i = 0; i < 16; i++) {
            float4 w4 = *(const float4*)&wsh[og * 16 + i][c];
            acc[i] += w4.x * x0 + w4.y * x1 + w4.z * x2 + w4.w * x3;
        }
    }
#pragma unroll
    for (int i = 0; i < 16; i++) {
        int o = ot * 64 + og * 16 + i;
        float v = acc[i] + qb[o];
        if (o < 128) v *= 0.5f;         // fold softmax scale into q and k
        qkv[((size_t)b * 192 + o) * LL + l0 + ll] = v;
    }
}

// ---------------------------------------------------------------------------
// Kernel 3: attention, flash-style online softmax.
// One thread per query row t (CH=16 -> q row + accumulator fit in regs).
// K/V tiles (16 x 128 each) staged in LDS; inner reads are wave-uniform
// float4 broadcasts (conflict-free).
// grid (16 t-tiles, 32 bh), block 128.
// ---------------------------------------------------------------------------
__global__ __launch_bounds__(128) void k_attn(const float* __restrict__ qkv,
                                              float* __restrict__ abuf) {
    int tt = blockIdx.x;   // 0..15
    int bh = blockIdx.y;   // 0..31
    int b = bh >> 2, h = bh & 3;
    int tid = threadIdx.x;
    int t = tt * 128 + tid;
    const float* qp = qkv + ((size_t)b * 192 + h * 16) * LL;
    const float* kp = qkv + ((size_t)b * 192 + 64 + h * 16) * LL;
    const float* vp = qkv + ((size_t)b * 192 + 128 + h * 16) * LL;

    float q[16];
#pragma unroll
    for (int c = 0; c < 16; c++) q[c] = qp[(size_t)c * LL + t];

    __shared__ float ks[16][128];
    __shared__ float vs[16][128];

    float m = -1e30f, lsum = 0.f;
    float acc[16];
#pragma unroll
    for (int c = 0; c < 16; c++) acc[c] = 0.f;

    for (int s0 = 0; s0 < LL; s0 += 128) {
#pragma unroll
        for (int k = 0; k < 4; k++) {
            int chunk = tid + k * 128;          // 0..511
            int c = chunk >> 5, l4 = chunk & 31;
            *(float4*)&ks[c][l4 * 4] =
                *(const float4*)(kp + (size_t)c * LL + s0 + l4 * 4);
            *(float4*)&vs[c][l4 * 4] =
                *(const float4*)(vp + (size_t)c * LL + s0 + l4 * 4);
        }
        __syncthreads();
        for (int j4 = 0; j4 < 32; j4++) {
            float sc0 = 0.f, sc1 = 0.f, sc2 = 0.f, sc3 = 0.f;
#pragma unroll
            for (int c = 0; c < 16; c++) {
                float4 kv = *(const float4*)&ks[c][j4 * 4];
                sc0 += q[c] * kv.x; sc1 += q[c] * kv.y;
                sc2 += q[c] * kv.z; sc3 += q[c] * kv.w;
            }
            float mx = fmaxf(fmaxf(sc0, sc1), fmaxf(sc2, sc3));
            if (mx > m) {
                float corr = __expf(m - mx);
                m = mx;
                lsum *= corr;
#pragma unroll
                for (int c = 0; c < 16; c++) acc[c] *= corr;
            }
            float p0 = __expf(sc0 - m), p1 = __expf(sc1 - m);
            float p2 = __expf(sc2 - m), p3 = __expf(sc3 - m);
            lsum += p0 + p1 + p2 + p3;
#pragma unroll
            for (int c = 0; c < 16; c++) {
                float4 vv = *(const float4*)&vs[c][j4 * 4];
                acc[c] += p0 * vv.x + p1 * vv.y + p2 * vv.z + p3 * vv.w;
            }
        }
        __syncthreads();
    }
    float rl = 1.0f / lsum;
#pragma unroll
    for (int c = 0; c < 16; c++)
        abuf[((size_t)bh * 16 + c) * LL + t] = acc[c] * rl;
}

// ---------------------------------------------------------------------------
// Kernel 4: proj conv1x1 + bias + residual. Tile 64 o x 64 l, K=64.
// grid (32 l-tiles, 8 b), block 256.
// ---------------------------------------------------------------------------
__global__ __launch_bounds__(256) void k_proj(const float* __restrict__ x,
                                              const float* __restrict__ abuf,
                                              const float* __restrict__ pw,
                                              const float* __restrict__ pb,
                                              float* __restrict__ out) {
    int lt = blockIdx.x;   // 0..31
    int b  = blockIdx.y;   // 0..7
    int tid = threadIdx.x;
    int l0 = lt * 64;
    __shared__ float as_[64][64];
    __shared__ float wsh[64][64];
#pragma unroll
    for (int k = 0; k < 4; k++) {
        int chunk = tid + k * 256;
        int c = chunk >> 4, l4 = chunk & 15;
        *(float4*)&as_[c][l4 * 4] =
            *(const float4*)(abuf + ((size_t)b * CC + c) * LL + l0 + l4 * 4);
        *(float4*)&wsh[c][l4 * 4] = *(const float4*)(pw + (size_t)chunk * 4);
    }
    __syncthreads();
    int ll = tid & 63, og = tid >> 6;
    float acc[16];
#pragma unroll
    for (int i = 0; i < 16; i++) acc[i] = 0.f;
    for (int c = 0; c < 64; c += 4) {
        float x0 = as_[c][ll], x1 = as_[c + 1][ll];
        float x2 = as_[c + 2][ll], x3 = as_[c + 3][ll];
#pragma unroll
        for (int i = 0; i < 16; i++) {
            float4 w4 = *(const float4*)&wsh[og * 16 + i][c];
            acc[i] += w4.x * x0 + w4.y * x1 + w4.z * x2 + w4.w * x3;
        }
    }
#pragma unroll
    for (int i = 0; i < 16; i++) {
        int o = og * 16 + i;
        size_t idx = ((size_t)b * CC + o) * LL + l0 + ll;
        out[idx] = x[idx] + acc[i] + pb[o];
    }
}

// ---------------------------------------------------------------------------
extern "C" void kernel_launch(void* const* d_in, const int* in_sizes, int n_in,
                              void* d_out, int out_size, void* d_ws, size_t ws_size,
                              hipStream_t stream) {
    const float* x   = (const float*)d_in[0];
    const float* gnw = (const float*)d_in[1];
    const float* gnb = (const float*)d_in[2];
    const float* qw  = (const float*)d_in[3];
    const float* qb  = (const float*)d_in[4];
    const float* pw  = (const float*)d_in[5];
    const float* pb  = (const float*)d_in[6];
    float* out = (float*)d_out;

    float* wsf   = (float*)d_ws;
    float* stats = wsf;                        // 64 floats
    float* qkv   = wsf + 64;                   // 8*192*2048 = 3,145,728 floats
    float* abuf  = qkv + (size_t)BB * 192 * LL; // 8*64*2048 = 1,048,576 floats

    hipLaunchKernelGGL(k_gnstats, dim3(32), dim3(256), 0, stream, x, stats);
    hipLaunchKernelGGL(k_qkv, dim3(32, 3, 8), dim3(256), 0, stream,
                       x, gnw, gnb, qw, qb, stats, qkv);
    hipLaunchKernelGGL(k_attn, dim3(16, 32), dim3(128), 0, stream, qkv, abuf);
    hipLaunchKernelGGL(k_proj, dim3(32, 8), dim3(256), 0, stream,
                       x, abuf, pw, pb, out);
}

// Round 2
// 153.140 us; speedup vs baseline: 3.8242x; 3.8242x over previous
//
#include <hip/hip_runtime.h>
#include <hip/hip_bf16.h>

#define LL 2048
#define CC 64
#define BB 8

typedef float f32x16 __attribute__((ext_vector_type(16)));
typedef short short8 __attribute__((ext_vector_type(8)));

__device__ __forceinline__ uint32_t pack2(float a, float b) {
    union { __hip_bfloat16 h; unsigned short s; } ua, ub;
    ua.h = __float2bfloat16(a);
    ub.h = __float2bfloat16(b);
    return (uint32_t)ua.s | ((uint32_t)ub.s << 16);
}

// ---------------------------------------------------------------------------
// Kernel 1: GroupNorm stats. One block per (b,g).
// ---------------------------------------------------------------------------
__global__ __launch_bounds__(256) void k_gnstats(const float* __restrict__ x,
                                                 float* __restrict__ stats) {
    int bg = blockIdx.x;  // 0..31
    const float4* p = (const float4*)(x + (size_t)bg * (16 * LL));
    float s1 = 0.f, s2 = 0.f;
    for (int i = threadIdx.x; i < 8192; i += 256) {
        float4 v = p[i];
        s1 += v.x + v.y + v.z + v.w;
        s2 += v.x * v.x + v.y * v.y + v.z * v.z + v.w * v.w;
    }
#pragma unroll
    for (int off = 32; off > 0; off >>= 1) {
        s1 += __shfl_down(s1, off, 64);
        s2 += __shfl_down(s2, off, 64);
    }
    __shared__ float r1[4], r2[4];
    int lane = threadIdx.x & 63, wv = threadIdx.x >> 6;
    if (lane == 0) { r1[wv] = s1; r2[wv] = s2; }
    __syncthreads();
    if (threadIdx.x == 0) {
        float sa = r1[0] + r1[1] + r1[2] + r1[3];
        float sb = r2[0] + r2[1] + r2[2] + r2[3];
        float mean = sa * (1.0f / 32768.0f);
        float var = sb * (1.0f / 32768.0f) - mean * mean;
        stats[bg * 2]     = mean;
        stats[bg * 2 + 1] = rsqrtf(var + 1e-5f);
    }
}

// ---------------------------------------------------------------------------
// Kernel 2: QKV conv1x1 with fused GroupNorm. Outputs bf16:
//   qt: [bh][t][16c]  (x0.5)   kt: [bh][s][16c]  (x0.5)   vb: [bh][16c][s]
// grid (32 l-tiles, 3 o-tiles, 8 b), block 256.
// ---------------------------------------------------------------------------
__global__ __launch_bounds__(256) void k_qkv(const float* __restrict__ x,
                                             const float* __restrict__ gnw,
                                             const float* __restrict__ gnb,
                                             const float* __restrict__ qw,
                                             const float* __restrict__ qb,
                                             const float* __restrict__ stats,
                                             unsigned short* __restrict__ qt,
                                             unsigned short* __restrict__ kt,
                                             unsigned short* __restrict__ vb) {
    int lt = blockIdx.x;   // 0..31
    int ot = blockIdx.y;   // 0..2  (q, k, v)
    int b  = blockIdx.z;   // 0..7
    int tid = threadIdx.x;
    int l0 = lt * 64;
    __shared__ float xs[64][68];     // padded: transpose reads conflict-light
    __shared__ float wsh[64][64];
#pragma unroll
    for (int k = 0; k < 4; k++) {
        int chunk = tid + k * 256;        // 0..1023
        int c = chunk >> 4, l4 = chunk & 15;
        float4 v = *(const float4*)(x + ((size_t)b * CC + c) * LL + l0 + l4 * 4);
        int g = c >> 4;
        float mean = stats[(b * 4 + g) * 2];
        float rstd = stats[(b * 4 + g) * 2 + 1];
        float wgt = gnw[c] * rstd;
        float bia = gnb[c] - mean * wgt;
        float4 o;
        o.x = v.x * wgt + bia; o.y = v.y * wgt + bia;
        o.z = v.z * wgt + bia; o.w = v.w * wgt + bia;
        *(float4*)&xs[c][l4 * 4] = o;
        *(float4*)&wsh[c][l4 * 4] =
            *(const float4*)(qw + ((size_t)(ot * 64 + c)) * CC + l4 * 4);
    }
    __syncthreads();
    int ll = tid & 63, og = tid >> 6;   // og uniform per wave
    float acc[16];
#pragma unroll
    for (int i = 0; i < 16; i++) acc[i] = 0.f;
    for (int c = 0; c < 64; c += 4) {
        float x0 = xs[c][ll], x1 = xs[c + 1][ll];
        float x2 = xs[c + 2][ll], x3 = xs[c + 3][ll];
#pragma unroll
        for (int i = 0; i < 16; i++) {
            float4 w4 = *(const float4*)&wsh[og * 16 + i][c];
            acc[i] += w4.x * x0 + w4.y * x1 + w4.z * x2 + w4.w * x3;
        }
    }
    if (ot < 2) {
        // q or k: thread owns 16 consecutive channels of head og at t=l0+ll.
        uint32_t w[8];
#pragma unroll
        for (int i = 0; i < 8; i++) {
            int o0 = ot * 64 + og * 16 + 2 * i;
            w[i] = pack2((acc[2 * i]     + qb[o0])     * 0.5f,
                         (acc[2 * i + 1] + qb[o0 + 1]) * 0.5f);
        }
        unsigned short* dst = (ot == 0 ? qt : kt);
        dst += ((size_t)(b * 4 + og)) * (LL * 16) + (size_t)(l0 + ll) * 16;
        *(uint4*)dst       = make_uint4(w[0], w[1], w[2], w[3]);
        *(uint4*)(dst + 8) = make_uint4(w[4], w[5], w[6], w[7]);
    } else {
        // v: transpose through LDS to [bh][c][s] bf16.
        __syncthreads();   // everyone done reading xs before overwrite
#pragma unroll
        for (int i = 0; i < 16; i++)
            xs[og * 16 + i][ll] = acc[i] + qb[128 + og * 16 + i];
        __syncthreads();
        int r = tid >> 2, sc = tid & 3;     // r: (head,chan) row 0..63
        const float* row = &xs[r][sc * 16];
        uint32_t w[8];
#pragma unroll
        for (int j = 0; j < 8; j++) w[j] = pack2(row[2 * j], row[2 * j + 1]);
        unsigned short* dst = vb + ((size_t)(b * 4 + (r >> 4))) * (16 * LL)
                              + (size_t)(r & 15) * LL + l0 + sc * 16;
        *(uint4*)dst       = make_uint4(w[0], w[1], w[2], w[3]);
        *(uint4*)(dst + 8) = make_uint4(w[4], w[5], w[6], w[7]);
    }
}

// ---------------------------------------------------------------------------
// Kernel 3: MFMA flash attention. 1 wave = 32 q-rows of one head.
// Swapped QK^T: d1 = mfma(K,Q) -> P^T tile, col=t lane-local softmax.
// PV: A-frag from P regs via partner shfl, B-frag = V direct from global.
// No LDS, no barriers. grid (16, 32 bh), block 256 (4 waves).
// ---------------------------------------------------------------------------
__global__ __launch_bounds__(256) void k_attn(const unsigned short* __restrict__ qt,
                                              const unsigned short* __restrict__ kt,
                                              const unsigned short* __restrict__ vb,
                                              float* __restrict__ abuf) {
    int wv = threadIdx.x >> 6;
    int lane = threadIdx.x & 63;
    int hi = lane >> 5, tlo = lane & 31;
    int bh = blockIdx.y;
    int t0 = (blockIdx.x * 4 + wv) * 32;

    const unsigned short* qp = qt + (size_t)bh * (LL * 16);
    const unsigned short* kp = kt + (size_t)bh * (LL * 16);
    const unsigned short* vp = vb + (size_t)bh * (16 * LL) + (size_t)(tlo & 15) * LL;

    short8 qf = *(const short8*)(qp + (size_t)(t0 + tlo) * 16 + 8 * hi);

    f32x16 d2 = {};
    float m = -1e30f, lsum = 0.f;

    for (int s0 = 0; s0 < LL; s0 += 32) {
        short8 kf  = *(const short8*)(kp + (size_t)(s0 + tlo) * 16 + 8 * hi);
        short8 vf0 = *(const short8*)(vp + s0 + 8 * hi);
        short8 vf1 = *(const short8*)(vp + s0 + 16 + 8 * hi);

        f32x16 z = {};
        f32x16 d1 = __builtin_amdgcn_mfma_f32_32x32x16_bf16(kf, qf, z, 0, 0, 0);

        // per-lane max over its 16 s-rows, combine with partner (same t)
        float pmax = d1[0];
#pragma unroll
        for (int r = 1; r < 16; r++) pmax = fmaxf(pmax, d1[r]);
        pmax = fmaxf(pmax, __shfl_xor(pmax, 32, 64));

        if (__any(pmax > m + 8.f)) {     // defer-max: rescale is rare
            float mn = fmaxf(m, pmax);
            float f = __expf(m - mn);
            m = mn;
            lsum *= f;
#pragma unroll
            for (int r = 0; r < 16; r++) {
                int row = (r & 3) + 8 * (r >> 2) + 4 * hi;
                d2[r] *= __shfl(f, row, 64);
            }
        }

        float p[16], ps = 0.f;
#pragma unroll
        for (int r = 0; r < 16; r++) { p[r] = __expf(d1[r] - m); ps += p[r]; }
        lsum += ps;

        // pack to bf16 pairs (consecutive s within lane's row set)
        uint32_t pk[8];
#pragma unroll
        for (int i = 0; i < 8; i++) pk[i] = pack2(p[2 * i], p[2 * i + 1]);

        // redistribute across partner lanes into A-fragment layout
        uint32_t w0 = __shfl_xor(pk[0], 32, 64), w1 = __shfl_xor(pk[1], 32, 64);
        uint32_t w2 = __shfl_xor(pk[2], 32, 64), w3 = __shfl_xor(pk[3], 32, 64);
        uint32_t w4 = __shfl_xor(pk[4], 32, 64), w5 = __shfl_xor(pk[5], 32, 64);
        uint32_t w6 = __shfl_xor(pk[6], 32, 64), w7 = __shfl_xor(pk[7], 32, 64);
        union { uint32_t u[4]; short8 s; } A1, A2;
        A1.u[0] = hi ? w2 : pk[0];
        A1.u[1] = hi ? w3 : pk[1];
        A1.u[2] = hi ? pk[2] : w0;
        A1.u[3] = hi ? pk[3] : w1;
        A2.u[0] = hi ? w6 : pk[4];
        A2.u[1] = hi ? w7 : pk[5];
        A2.u[2] = hi ? pk[6] : w4;
        A2.u[3] = hi ? pk[7] : w5;

        d2 = __builtin_amdgcn_mfma_f32_32x32x16_bf16(A1.s, vf0, d2, 0, 0, 0);
        d2 = __builtin_amdgcn_mfma_f32_32x32x16_bf16(A2.s, vf1, d2, 0, 0, 0);
    }

    float ls = lsum + __shfl_xor(lsum, 32, 64);
    float rl = 1.0f / ls;
    float scn[16];
#pragma unroll
    for (int r = 0; r < 16; r++) {       // all lanes active for the shfl
        int row = (r & 3) + 8 * (r >> 2) + 4 * hi;
        scn[r] = __shfl(rl, row, 64);
    }
    if (tlo < 16) {
        float* op = abuf + ((size_t)bh * 16 + tlo) * LL + t0;
#pragma unroll
        for (int r = 0; r < 16; r++) {
            int row = (r & 3) + 8 * (r >> 2) + 4 * hi;
            op[row] = d2[r] * scn[r];
        }
    }
}

// ---------------------------------------------------------------------------
// Kernel 4: proj conv1x1 + bias + residual (fp32, unchanged).
// ---------------------------------------------------------------------------
__global__ __launch_bounds__(256) void k_proj(const float* __restrict__ x,
                                              const float* __restrict__ abuf,
                                              const float* __restrict__ pw,
                                              const float* __restrict__ pb,
                                              float* __restrict__ out) {
    int lt = blockIdx.x;   // 0..31
    int b  = blockIdx.y;   // 0..7
    int tid = threadIdx.x;
    int l0 = lt * 64;
    __shared__ float as_[64][64];
    __shared__ float wsh[64][64];
#pragma unroll
    for (int k = 0; k < 4; k++) {
        int chunk = tid + k * 256;
        int c = chunk >> 4, l4 = chunk & 15;
        *(float4*)&as_[c][l4 * 4] =
            *(const float4*)(abuf + ((size_t)b * CC + c) * LL + l0 + l4 * 4);
        *(float4*)&wsh[c][l4 * 4] = *(const float4*)(pw + (size_t)chunk * 4);
    }
    __syncthreads();
    int ll = tid & 63, og = tid >> 6;
    float acc[16];
#pragma unroll
    for (int i = 0; i < 16; i++) acc[i] = 0.f;
    for (int c = 0; c < 64; c += 4) {
        float x0 = as_[c][ll], x1 = as_[c + 1][ll];
        float x2 = as_[c + 2][ll], x3 = as_[c + 3][ll];
#pragma unroll
        for (int i = 0; i < 16; i++) {
            float4 w4 = *(const float4*)&wsh[og * 16 + i][c];
            acc[i] += w4.x * x0 + w4.y * x1 + w4.z * x2 + w4.w * x3;
        }
    }
#pragma unroll
    for (int i = 0; i < 16; i++) {
        int o = og * 16 + i;
        size_t idx = ((size_t)b * CC + o) * LL + l0 + ll;
        out[idx] = x[idx] + acc[i] + pb[o];
    }
}

// ---------------------------------------------------------------------------
extern "C" void kernel_launch(void* const* d_in, const int* in_sizes, int n_in,
                              void* d_out, int out_size, void* d_ws, size_t ws_size,
                              hipStream_t stream) {
    const float* x   = (const float*)d_in[0];
    const float* gnw = (const float*)d_in[1];
    const float* gnb = (const float*)d_in[2];
    const float* qw  = (const float*)d_in[3];
    const float* qb  = (const float*)d_in[4];
    const float* pw  = (const float*)d_in[5];
    const float* pb  = (const float*)d_in[6];
    float* out = (float*)d_out;

    float* wsf   = (float*)d_ws;
    float* stats = wsf;                                  // 64 floats
    unsigned short* qt = (unsigned short*)(wsf + 64);    // 32*2048*16 bf16
    unsigned short* kt = qt + (size_t)32 * LL * 16;
    unsigned short* vb = kt + (size_t)32 * LL * 16;
    float* abuf = (float*)(vb + (size_t)32 * LL * 16);   // 8*64*2048 f32

    hipLaunchKernelGGL(k_gnstats, dim3(32), dim3(256), 0, stream, x, stats);
    hipLaunchKernelGGL(k_qkv, dim3(32, 3, 8), dim3(256), 0, stream,
                       x, gnw, gnb, qw, qb, stats, qt, kt, vb);
    hipLaunchKernelGGL(k_attn, dim3(16, 32), dim3(256), 0, stream, qt, kt, vb, abuf);
    hipLaunchKernelGGL(k_proj, dim3(32, 8), dim3(256), 0, stream,
                       x, abuf, pw, pb, out);
}

// Round 3
// 140.374 us; speedup vs baseline: 4.1720x; 1.0909x over previous
//
#include <hip/hip_runtime.h>
#include <hip/hip_bf16.h>

#define LL 2048

typedef float f32x16 __attribute__((ext_vector_type(16)));
typedef float f32x4 __attribute__((ext_vector_type(4)));
typedef short short8 __attribute__((ext_vector_type(8)));

__device__ __forceinline__ float exp2_fast(float x) {
    float r;
    asm volatile("v_exp_f32 %0, %1" : "=v"(r) : "v"(x));
    return r;
}

__device__ __forceinline__ uint32_t pack2(float a, float b) {
    union { __hip_bfloat16 h; unsigned short s; } ua, ub;
    ua.h = __float2bfloat16(a);
    ub.h = __float2bfloat16(b);
    return (uint32_t)ua.s | ((uint32_t)ub.s << 16);
}

// ---------------------------------------------------------------------------
// Kernel 1: GroupNorm raw sums. 4 blocks per (b,g), atomicAdd into stats.
// stats[bg*2] = sum x, stats[bg*2+1] = sum x^2 (finalized inline in k_qkv).
// ---------------------------------------------------------------------------
__global__ __launch_bounds__(256) void k_gnstats(const float* __restrict__ x,
                                                 float* __restrict__ stats) {
    int bg = blockIdx.x >> 2, part = blockIdx.x & 3;
    const f32x4* p = (const f32x4*)(x + (size_t)bg * (16 * LL)) + part * 2048;
    float s1 = 0.f, s2 = 0.f;
    for (int i = threadIdx.x; i < 2048; i += 256) {
        f32x4 v = p[i];
        s1 += v[0] + v[1] + v[2] + v[3];
        s2 += v[0] * v[0] + v[1] * v[1] + v[2] * v[2] + v[3] * v[3];
    }
#pragma unroll
    for (int off = 32; off > 0; off >>= 1) {
        s1 += __shfl_down(s1, off, 64);
        s2 += __shfl_down(s2, off, 64);
    }
    __shared__ float r1[4], r2[4];
    int lane = threadIdx.x & 63, wv = threadIdx.x >> 6;
    if (lane == 0) { r1[wv] = s1; r2[wv] = s2; }
    __syncthreads();
    if (threadIdx.x == 0) {
        atomicAdd(&stats[bg * 2],     r1[0] + r1[1] + r1[2] + r1[3]);
        atomicAdd(&stats[bg * 2 + 1], r2[0] + r2[1] + r2[2] + r2[3]);
    }
}

// ---------------------------------------------------------------------------
// Kernel 2: QKV conv1x1 with fused GroupNorm. Thread = 4 chan x 4 pos.
// Outputs bf16: qt [bh][t][16c] (*0.5), kt [bh][s][16c] (*0.5*log2e),
// vb [bh][16c][s] (written directly -- no LDS transpose).
// grid (32 l-tiles, 3 ot, 8 b), block 256.
// ---------------------------------------------------------------------------
__global__ __launch_bounds__(256) void k_qkv(const float* __restrict__ x,
                                             const float* __restrict__ gnw,
                                             const float* __restrict__ gnb,
                                             const float* __restrict__ qw,
                                             const float* __restrict__ qb,
                                             const float* __restrict__ stats,
                                             unsigned short* __restrict__ qt,
                                             unsigned short* __restrict__ kt,
                                             unsigned short* __restrict__ vb) {
    int lt = blockIdx.x;   // 0..31
    int ot = blockIdx.y;   // 0..2  (q, k, v)
    int b  = blockIdx.z;   // 0..7
    int tid = threadIdx.x;
    int l0 = lt * 64;
    __shared__ float xs[64][68];
    __shared__ float wsh[64][68];
#pragma unroll
    for (int k = 0; k < 4; k++) {
        int chunk = tid + k * 256;        // 0..1023
        int c = chunk >> 4, l4 = chunk & 15;
        f32x4 v = *(const f32x4*)(x + ((size_t)b * 64 + c) * LL + l0 + l4 * 4);
        int g = c >> 4;
        float s1 = stats[(b * 4 + g) * 2], s2 = stats[(b * 4 + g) * 2 + 1];
        float mean = s1 * (1.0f / 32768.0f);
        float var  = s2 * (1.0f / 32768.0f) - mean * mean;
        float rstd = rsqrtf(var + 1e-5f);
        float wgt = gnw[c] * rstd;
        float bia = gnb[c] - mean * wgt;
        f32x4 o;
        o[0] = v[0] * wgt + bia; o[1] = v[1] * wgt + bia;
        o[2] = v[2] * wgt + bia; o[3] = v[3] * wgt + bia;
        *(f32x4*)&xs[c][l4 * 4] = o;
        *(f32x4*)&wsh[c][l4 * 4] =
            *(const f32x4*)(qw + (size_t)(ot * 64 + c) * 64 + l4 * 4);
    }
    __syncthreads();
    int og = tid & 15, lg = tid >> 4;    // 4 channels (og*4..), 4 pos (lg*4..)
    float acc[4][4] = {};
    for (int c = 0; c < 64; c += 4) {
        f32x4 xv0 = *(const f32x4*)&xs[c    ][lg * 4];
        f32x4 xv1 = *(const f32x4*)&xs[c + 1][lg * 4];
        f32x4 xv2 = *(const f32x4*)&xs[c + 2][lg * 4];
        f32x4 xv3 = *(const f32x4*)&xs[c + 3][lg * 4];
#pragma unroll
        for (int i = 0; i < 4; i++) {
            f32x4 w4 = *(const f32x4*)&wsh[og * 4 + i][c];
#pragma unroll
            for (int j = 0; j < 4; j++)
                acc[i][j] += w4[0] * xv0[j] + w4[1] * xv1[j]
                           + w4[2] * xv2[j] + w4[3] * xv3[j];
        }
    }
    int head = og >> 2, cb = (og & 3) * 4;
    if (ot < 2) {
        float sc = (ot == 0) ? 0.5f : 0.72134752f;   // k also carries log2(e)
        float b0 = qb[ot * 64 + og * 4],     b1 = qb[ot * 64 + og * 4 + 1];
        float b2 = qb[ot * 64 + og * 4 + 2], b3 = qb[ot * 64 + og * 4 + 3];
        unsigned short* dst = (ot == 0 ? qt : kt) + (size_t)(b * 4 + head) * (LL * 16);
#pragma unroll
        for (int j = 0; j < 4; j++) {
            uint32_t lo = pack2((acc[0][j] + b0) * sc, (acc[1][j] + b1) * sc);
            uint32_t hw = pack2((acc[2][j] + b2) * sc, (acc[3][j] + b3) * sc);
            *(uint2*)(dst + (size_t)(l0 + lg * 4 + j) * 16 + cb) = make_uint2(lo, hw);
        }
    } else {
        unsigned short* dst = vb + (size_t)(b * 4 + head) * (16 * LL) + l0 + lg * 4;
#pragma unroll
        for (int i = 0; i < 4; i++) {
            float bi = qb[128 + og * 4 + i];
            uint32_t lo = pack2(acc[i][0] + bi, acc[i][1] + bi);
            uint32_t hw = pack2(acc[i][2] + bi, acc[i][3] + bi);
            *(uint2*)(dst + (size_t)(cb + i) * LL) = make_uint2(lo, hw);
        }
    }
}

// ---------------------------------------------------------------------------
// Kernel 3: MFMA flash attention, split-K x4 with in-block combine.
// 4 waves/block, same 32 q-rows, each takes 512 of the 2048 s-positions.
// Waves 1-3 dump (O,m,l) to LDS; wave 0 merges + normalizes.
// grid (64 t-tiles, 32 bh), block 256.
// ---------------------------------------------------------------------------
__global__ __launch_bounds__(256) void k_attn(const unsigned short* __restrict__ qt,
                                              const unsigned short* __restrict__ kt,
                                              const unsigned short* __restrict__ vb,
                                              float* __restrict__ abuf) {
    int wv = threadIdx.x >> 6;          // split index 0..3
    int lane = threadIdx.x & 63;
    int hi = lane >> 5, tlo = lane & 31;
    int bh = blockIdx.y;
    int t0 = blockIdx.x * 32;

    __shared__ float lds_d2[3][32][17];
    __shared__ float lds_m[3][32];
    __shared__ float lds_l[3][32];

    const unsigned short* qp = qt + (size_t)bh * (LL * 16);
    const unsigned short* kp = kt + (size_t)bh * (LL * 16);
    const unsigned short* vp = vb + (size_t)bh * (16 * LL) + (size_t)(tlo & 15) * LL;

    short8 qf = *(const short8*)(qp + (size_t)(t0 + tlo) * 16 + 8 * hi);

    f32x16 d2 = {};
    float m = -1e30f, lsum = 0.f;

    int sbeg = wv * 512;
    for (int s0 = sbeg; s0 < sbeg + 512; s0 += 32) {
        short8 kf  = *(const short8*)(kp + (size_t)(s0 + tlo) * 16 + 8 * hi);
        short8 vf0 = *(const short8*)(vp + s0 + 8 * hi);
        short8 vf1 = *(const short8*)(vp + s0 + 16 + 8 * hi);

        f32x16 z = {};
        f32x16 d1 = __builtin_amdgcn_mfma_f32_32x32x16_bf16(kf, qf, z, 0, 0, 0);

        // per-lane max over 16 s-rows (tree), combine with partner (same t)
        float a0 = fmaxf(d1[0], d1[1]),   a1 = fmaxf(d1[2], d1[3]);
        float a2 = fmaxf(d1[4], d1[5]),   a3 = fmaxf(d1[6], d1[7]);
        float a4 = fmaxf(d1[8], d1[9]),   a5 = fmaxf(d1[10], d1[11]);
        float a6 = fmaxf(d1[12], d1[13]), a7 = fmaxf(d1[14], d1[15]);
        float pmax = fmaxf(fmaxf(fmaxf(a0, a1), fmaxf(a2, a3)),
                           fmaxf(fmaxf(a4, a5), fmaxf(a6, a7)));
        pmax = fmaxf(pmax, __shfl_xor(pmax, 32, 64));

        if (__any(pmax > m + 8.f)) {     // defer-max (log2 units)
            float mn = fmaxf(m, pmax);
            float f = exp2_fast(m - mn);
            m = mn;
            lsum *= f;
#pragma unroll
            for (int r = 0; r < 16; r++) {
                int row = (r & 3) + 8 * (r >> 2) + 4 * hi;
                d2[r] *= __shfl(f, row, 64);
            }
        }

        float p[16], ps = 0.f;
#pragma unroll
        for (int r = 0; r < 16; r++) { p[r] = exp2_fast(d1[r] - m); ps += p[r]; }
        lsum += ps;

        uint32_t pk[8];
#pragma unroll
        for (int i = 0; i < 8; i++) pk[i] = pack2(p[2 * i], p[2 * i + 1]);

        uint32_t w0 = __shfl_xor(pk[0], 32, 64), w1 = __shfl_xor(pk[1], 32, 64);
        uint32_t w2 = __shfl_xor(pk[2], 32, 64), w3 = __shfl_xor(pk[3], 32, 64);
        uint32_t w4 = __shfl_xor(pk[4], 32, 64), w5 = __shfl_xor(pk[5], 32, 64);
        uint32_t w6 = __shfl_xor(pk[6], 32, 64), w7 = __shfl_xor(pk[7], 32, 64);
        union { uint32_t u[4]; short8 s; } A1, A2;
        A1.u[0] = hi ? w2 : pk[0];
        A1.u[1] = hi ? w3 : pk[1];
        A1.u[2] = hi ? pk[2] : w0;
        A1.u[3] = hi ? pk[3] : w1;
        A2.u[0] = hi ? w6 : pk[4];
        A2.u[1] = hi ? w7 : pk[5];
        A2.u[2] = hi ? pk[6] : w4;
        A2.u[3] = hi ? pk[7] : w5;

        d2 = __builtin_amdgcn_mfma_f32_32x32x16_bf16(A1.s, vf0, d2, 0, 0, 0);
        d2 = __builtin_amdgcn_mfma_f32_32x32x16_bf16(A2.s, vf1, d2, 0, 0, 0);
    }

    float ls = lsum + __shfl_xor(lsum, 32, 64);

    if (wv > 0) {
        int w = wv - 1;
#pragma unroll
        for (int r = 0; r < 16; r++) {
            int row = (r & 3) + 8 * (r >> 2) + 4 * hi;
            if (tlo < 16) lds_d2[w][row][tlo] = d2[r];
        }
        if (hi == 0) { lds_m[w][tlo] = m; lds_l[w][tlo] = ls; }
    }
    __syncthreads();
    if (wv == 0) {
        float m1 = lds_m[0][tlo], m2 = lds_m[1][tlo], m3 = lds_m[2][tlo];
        float mx = fmaxf(fmaxf(m, m1), fmaxf(m2, m3));
        float f0 = exp2_fast(m - mx),  f1 = exp2_fast(m1 - mx);
        float f2 = exp2_fast(m2 - mx), f3 = exp2_fast(m3 - mx);
        float lden = ls * f0 + lds_l[0][tlo] * f1
                   + lds_l[1][tlo] * f2 + lds_l[2][tlo] * f3;
        float rl = 1.0f / lden;
        float* op = abuf + ((size_t)bh * 16 + tlo) * LL + t0;
        int tc = tlo & 15;
#pragma unroll
        for (int r = 0; r < 16; r++) {
            int row = (r & 3) + 8 * (r >> 2) + 4 * hi;
            float g0 = __shfl(f0, row, 64), g1 = __shfl(f1, row, 64);
            float g2 = __shfl(f2, row, 64), g3 = __shfl(f3, row, 64);
            float grl = __shfl(rl, row, 64);
            float acc = d2[r] * g0 + lds_d2[0][row][tc] * g1
                      + lds_d2[1][row][tc] * g2 + lds_d2[2][row][tc] * g3;
            if (tlo < 16) op[row] = acc * grl;
        }
    }
}

// ---------------------------------------------------------------------------
// Kernel 4: proj conv1x1 + bias + residual. Tile 64 o x 32 l (2x blocks).
// grid (64 l-tiles, 8 b), block 256.
// ---------------------------------------------------------------------------
__global__ __launch_bounds__(256) void k_proj(const float* __restrict__ x,
                                              const float* __restrict__ abuf,
                                              const float* __restrict__ pw,
                                              const float* __restrict__ pb,
                                              float* __restrict__ out) {
    int lt = blockIdx.x;   // 0..63
    int b  = blockIdx.y;   // 0..7
    int tid = threadIdx.x;
    int l0 = lt * 32;
    __shared__ float as_[64][36];
    __shared__ float wsh[64][68];
#pragma unroll
    for (int k = 0; k < 2; k++) {
        int chunk = tid + k * 256;   // 0..511
        int c = chunk >> 3, l4 = chunk & 7;
        *(f32x4*)&as_[c][l4 * 4] =
            *(const f32x4*)(abuf + ((size_t)b * 64 + c) * LL + l0 + l4 * 4);
    }
#pragma unroll
    for (int k = 0; k < 4; k++) {
        int chunk = tid + k * 256;
        int r = chunk >> 4, c4 = chunk & 15;
        *(f32x4*)&wsh[r][c4 * 4] = *(const f32x4*)(pw + (size_t)r * 64 + c4 * 4);
    }
    __syncthreads();
    int og = tid >> 5, ll = tid & 31;
    float acc[8] = {};
    for (int c = 0; c < 64; c += 4) {
        float x0 = as_[c][ll], x1 = as_[c + 1][ll];
        float x2 = as_[c + 2][ll], x3 = as_[c + 3][ll];
#pragma unroll
        for (int i = 0; i < 8; i++) {
            f32x4 w4 = *(const f32x4*)&wsh[og * 8 + i][c];
            acc[i] += w4[0] * x0 + w4[1] * x1 + w4[2] * x2 + w4[3] * x3;
        }
    }
#pragma unroll
    for (int i = 0; i < 8; i++) {
        int o = og * 8 + i;
        size_t idx = ((size_t)b * 64 + o) * LL + l0 + ll;
        out[idx] = x[idx] + acc[i] + pb[o];
    }
}

// ---------------------------------------------------------------------------
extern "C" void kernel_launch(void* const* d_in, const int* in_sizes, int n_in,
                              void* d_out, int out_size, void* d_ws, size_t ws_size,
                              hipStream_t stream) {
    const float* x   = (const float*)d_in[0];
    const float* gnw = (const float*)d_in[1];
    const float* gnb = (const float*)d_in[2];
    const float* qw  = (const float*)d_in[3];
    const float* qb  = (const float*)d_in[4];
    const float* pw  = (const float*)d_in[5];
    const float* pb  = (const float*)d_in[6];
    float* out = (float*)d_out;

    float* wsf   = (float*)d_ws;
    float* stats = wsf;                                  // 64 floats (raw sums)
    unsigned short* qt = (unsigned short*)(wsf + 64);    // 32*2048*16 bf16
    unsigned short* kt = qt + (size_t)32 * LL * 16;
    unsigned short* vb = kt + (size_t)32 * LL * 16;
    float* abuf = (float*)(vb + (size_t)32 * LL * 16);   // 8*64*2048 f32

    hipMemsetAsync(stats, 0, 64 * sizeof(float), stream);
    hipLaunchKernelGGL(k_gnstats, dim3(128), dim3(256), 0, stream, x, stats);
    hipLaunchKernelGGL(k_qkv, dim3(32, 3, 8), dim3(256), 0, stream,
                       x, gnw, gnb, qw, qb, stats, qt, kt, vb);
    hipLaunchKernelGGL(k_attn, dim3(64, 32), dim3(256), 0, stream, qt, kt, vb, abuf);
    hipLaunchKernelGGL(k_proj, dim3(64, 8), dim3(256), 0, stream,
                       x, abuf, pw, pb, out);
}

// Round 5
// 125.682 us; speedup vs baseline: 4.6597x; 1.1169x over previous
//
#include <hip/hip_runtime.h>
#include <hip/hip_bf16.h>

#define LL 2048

typedef float f32x16 __attribute__((ext_vector_type(16)));
typedef float f32x4 __attribute__((ext_vector_type(4)));
typedef short short8 __attribute__((ext_vector_type(8)));

__device__ __forceinline__ float exp2_fast(float x) {
    float r;
    asm volatile("v_exp_f32 %0, %1" : "=v"(r) : "v"(x));
    return r;
}

__device__ __forceinline__ uint32_t pack2(float a, float b) {
    union { __hip_bfloat16 h; unsigned short s; } ua, ub;
    ua.h = __float2bfloat16(a);
    ub.h = __float2bfloat16(b);
    return (uint32_t)ua.s | ((uint32_t)ub.s << 16);
}

__device__ __forceinline__ unsigned short bf16of(float a) {
    union { __hip_bfloat16 h; unsigned short s; } u;
    u.h = __float2bfloat16(a);
    return u.s;
}

// ---------------------------------------------------------------------------
// Kernel 1: GroupNorm raw sums. 4 blocks per (b,g), atomicAdd into stats.
// ---------------------------------------------------------------------------
__global__ __launch_bounds__(256) void k_gnstats(const float* __restrict__ x,
                                                 float* __restrict__ stats) {
    int bg = blockIdx.x >> 2, part = blockIdx.x & 3;
    const f32x4* p = (const f32x4*)(x + (size_t)bg * (16 * LL)) + part * 2048;
    float s1 = 0.f, s2 = 0.f;
    for (int i = threadIdx.x; i < 2048; i += 256) {
        f32x4 v = p[i];
        s1 += v[0] + v[1] + v[2] + v[3];
        s2 += v[0] * v[0] + v[1] * v[1] + v[2] * v[2] + v[3] * v[3];
    }
#pragma unroll
    for (int off = 32; off > 0; off >>= 1) {
        s1 += __shfl_down(s1, off, 64);
        s2 += __shfl_down(s2, off, 64);
    }
    __shared__ float r1[4], r2[4];
    int lane = threadIdx.x & 63, wv = threadIdx.x >> 6;
    if (lane == 0) { r1[wv] = s1; r2[wv] = s2; }
    __syncthreads();
    if (threadIdx.x == 0) {
        atomicAdd(&stats[bg * 2],     r1[0] + r1[1] + r1[2] + r1[3]);
        atomicAdd(&stats[bg * 2 + 1], r2[0] + r2[1] + r2[2] + r2[3]);
    }
}

// ---------------------------------------------------------------------------
// Kernel 2: QKV conv1x1 as bf16 MFMA GEMM with fused GroupNorm.
// A = w [o][c] (XOR-swizzled LDS), B = xn [l][c] (XOR-swizzled LDS).
// Outputs: qt [bh][t][16c] (*0.5), kt [bh][s][16c] (*0.5*log2e),
//          vb [bh][16c][s].
// grid (32 lt, 3 ot, 8 b), block 256 (4 waves: 2 o-tiles x 2 l-tiles).
// ---------------------------------------------------------------------------
__global__ __launch_bounds__(256) void k_qkv(const float* __restrict__ x,
                                             const float* __restrict__ gnw,
                                             const float* __restrict__ gnb,
                                             const float* __restrict__ qw,
                                             const float* __restrict__ qb,
                                             const float* __restrict__ stats,
                                             unsigned short* __restrict__ qt,
                                             unsigned short* __restrict__ kt,
                                             unsigned short* __restrict__ vb) {
    int lt = blockIdx.x;   // 0..31
    int ot = blockIdx.y;   // 0..2  (q, k, v)
    int b  = blockIdx.z;   // 0..7
    int tid = threadIdx.x;
    int l0 = lt * 64;
    __shared__ unsigned short xs[64 * 64];   // [l][c], short idx c ^ ((l&7)<<3)
    __shared__ unsigned short ws[64 * 64];   // [o][c], short idx c ^ ((o&7)<<3)

#pragma unroll
    for (int k = 0; k < 4; k++) {
        int chunk = tid + k * 256;        // 0..1023
        int c = chunk >> 4, l4 = chunk & 15;
        f32x4 v = *(const f32x4*)(x + ((size_t)b * 64 + c) * LL + l0 + l4 * 4);
        int g = c >> 4;
        float s1 = stats[(b * 4 + g) * 2], s2 = stats[(b * 4 + g) * 2 + 1];
        float mean = s1 * (1.0f / 32768.0f);
        float var  = s2 * (1.0f / 32768.0f) - mean * mean;
        float rstd = rsqrtf(var + 1e-5f);
        float wgt = gnw[c] * rstd;
        float bia = gnb[c] - mean * wgt;
#pragma unroll
        for (int j = 0; j < 4; j++) {
            int l = l4 * 4 + j;
            xs[l * 64 + (c ^ ((l & 7) << 3))] = bf16of(v[j] * wgt + bia);
        }
        // weight tile
        int o = c, c4 = l4;
        f32x4 wv4 = *(const f32x4*)(qw + (size_t)(ot * 64 + o) * 64 + c4 * 4);
        uint2 pw2 = make_uint2(pack2(wv4[0], wv4[1]), pack2(wv4[2], wv4[3]));
        *(uint2*)&ws[o * 64 + ((c4 * 4) ^ ((o & 7) << 3))] = pw2;
    }
    __syncthreads();

    int wv_ = tid >> 6, lane = tid & 63, hi = lane >> 5, tl = lane & 31;
    int o0 = (wv_ & 1) * 32, lw = (wv_ >> 1) * 32;
    int arow = o0 + tl, brow = lw + tl;
    f32x16 acc = {};
#pragma unroll
    for (int kk = 0; kk < 4; kk++) {
        int cb = kk * 16 + hi * 8;   // short offset of k-chunk
        short8 af = *(const short8*)&ws[arow * 64 + (cb ^ ((arow & 7) << 3))];
        short8 bf = *(const short8*)&xs[brow * 64 + (cb ^ ((brow & 7) << 3))];
        acc = __builtin_amdgcn_mfma_f32_32x32x16_bf16(af, bf, acc, 0, 0, 0);
    }

    int t = l0 + lw + tl;            // global l (column) for this lane
    if (ot < 2) {
        float sc = ot ? 0.72134752f : 0.5f;   // k also carries log2(e)
        unsigned short* base = (ot ? kt : qt) + (size_t)(b * 4) * (LL * 16);
#pragma unroll
        for (int g = 0; g < 4; g++) {
            int ob = o0 + 8 * g + 4 * hi;     // 4 consecutive o from here
            float v0 = (acc[4 * g]     + qb[ot * 64 + ob])     * sc;
            float v1 = (acc[4 * g + 1] + qb[ot * 64 + ob + 1]) * sc;
            float v2 = (acc[4 * g + 2] + qb[ot * 64 + ob + 2]) * sc;
            float v3 = (acc[4 * g + 3] + qb[ot * 64 + ob + 3]) * sc;
            uint2 pkv = make_uint2(pack2(v0, v1), pack2(v2, v3));
            *(uint2*)(base + (size_t)(ob >> 4) * (LL * 16) + (size_t)t * 16 + (ob & 15)) = pkv;
        }
    } else {
        unsigned short* base = vb + (size_t)(b * 4) * (16 * LL);
#pragma unroll
        for (int r = 0; r < 16; r++) {
            int o = o0 + (r & 3) + 8 * (r >> 2) + 4 * hi;
            base[(size_t)(o >> 4) * (16 * LL) + (size_t)(o & 15) * LL + t] =
                bf16of(acc[r] + qb[128 + o]);
        }
    }
}

// ---------------------------------------------------------------------------
// Kernel 3: MFMA flash attention, fixed-max (m=0) softmax, split-K x4.
// p = exp2(score) directly (exact in f32; |score_log2| bounded << 110).
// P->A-fragment repack via shfl_xor (verified R2/R3 path).
// Output bf16 abuf [b*64+c][t]. grid (64 t-tiles, 32 bh), block 256.
// ---------------------------------------------------------------------------
__global__ __launch_bounds__(256) void k_attn(const unsigned short* __restrict__ qt,
                                              const unsigned short* __restrict__ kt,
                                              const unsigned short* __restrict__ vb,
                                              unsigned short* __restrict__ abuf) {
    int wv = threadIdx.x >> 6;          // split index 0..3
    int lane = threadIdx.x & 63;
    int hi = lane >> 5, tlo = lane & 31;
    int bh = blockIdx.y;
    int t0 = blockIdx.x * 32;

    __shared__ float lds_d2[3][32][17];
    __shared__ float lds_l[3][32];

    const unsigned short* qp = qt + (size_t)bh * (LL * 16);
    const unsigned short* kp = kt + (size_t)bh * (LL * 16);
    const unsigned short* vp = vb + (size_t)bh * (16 * LL) + (size_t)(tlo & 15) * LL;

    short8 qf = *(const short8*)(qp + (size_t)(t0 + tlo) * 16 + 8 * hi);

    f32x16 d2 = {};
    float lsum = 0.f;

    int sbeg = wv * 512;
    for (int s0 = sbeg; s0 < sbeg + 512; s0 += 32) {
        short8 kf  = *(const short8*)(kp + (size_t)(s0 + tlo) * 16 + 8 * hi);
        short8 vf0 = *(const short8*)(vp + s0 + 8 * hi);
        short8 vf1 = *(const short8*)(vp + s0 + 16 + 8 * hi);

        f32x16 z = {};
        f32x16 d1 = __builtin_amdgcn_mfma_f32_32x32x16_bf16(kf, qf, z, 0, 0, 0);

        float p[16], ps = 0.f;
#pragma unroll
        for (int r = 0; r < 16; r++) { p[r] = exp2_fast(d1[r]); ps += p[r]; }
        lsum += ps;

        uint32_t pk[8];
#pragma unroll
        for (int i = 0; i < 8; i++) pk[i] = pack2(p[2 * i], p[2 * i + 1]);

        // redistribute across partner lanes into A-fragment layout (R2/R3)
        uint32_t w0 = __shfl_xor(pk[0], 32, 64), w1 = __shfl_xor(pk[1], 32, 64);
        uint32_t w2 = __shfl_xor(pk[2], 32, 64), w3 = __shfl_xor(pk[3], 32, 64);
        uint32_t w4 = __shfl_xor(pk[4], 32, 64), w5 = __shfl_xor(pk[5], 32, 64);
        uint32_t w6 = __shfl_xor(pk[6], 32, 64), w7 = __shfl_xor(pk[7], 32, 64);
        union { uint32_t u[4]; short8 s; } A1, A2;
        A1.u[0] = hi ? w2 : pk[0];
        A1.u[1] = hi ? w3 : pk[1];
        A1.u[2] = hi ? pk[2] : w0;
        A1.u[3] = hi ? pk[3] : w1;
        A2.u[0] = hi ? w6 : pk[4];
        A2.u[1] = hi ? w7 : pk[5];
        A2.u[2] = hi ? pk[6] : w4;
        A2.u[3] = hi ? pk[7] : w5;

        d2 = __builtin_amdgcn_mfma_f32_32x32x16_bf16(A1.s, vf0, d2, 0, 0, 0);
        d2 = __builtin_amdgcn_mfma_f32_32x32x16_bf16(A2.s, vf1, d2, 0, 0, 0);
    }

    float ls = lsum + __shfl_xor(lsum, 32, 64);   // total partial-l for t=tlo

    if (wv > 0) {
        int w = wv - 1;
#pragma unroll
        for (int r = 0; r < 16; r++) {
            int row = (r & 3) + 8 * (r >> 2) + 4 * hi;
            if (tlo < 16) lds_d2[w][row][tlo] = d2[r];
        }
        if (hi == 0) lds_l[w][tlo] = ls;
    }
    __syncthreads();
    if (wv == 0) {
        float lall = ls + lds_l[0][tlo] + lds_l[1][tlo] + lds_l[2][tlo];
        float rl = 1.0f / lall;                   // reciprocal for own t
        int tc = tlo & 15;
        unsigned short* op = abuf + ((size_t)bh * 16 + tlo) * LL + t0;
        float v[16];
#pragma unroll
        for (int r = 0; r < 16; r++) {            // all lanes run (shfl)
            int row = (r & 3) + 8 * (r >> 2) + 4 * hi;
            float osum = d2[r] + lds_d2[0][row][tc]
                       + lds_d2[1][row][tc] + lds_d2[2][row][tc];
            v[r] = osum * __shfl(rl, row, 64);
        }
        if (tlo < 16) {
#pragma unroll
            for (int g = 0; g < 4; g++) {
                uint2 pkv = make_uint2(pack2(v[4 * g], v[4 * g + 1]),
                                       pack2(v[4 * g + 2], v[4 * g + 3]));
                *(uint2*)(op + 8 * g + 4 * hi) = pkv;
            }
        }
    }
}

// ---------------------------------------------------------------------------
// Kernel 4: proj conv1x1 as bf16 MFMA GEMM + bias + fp32 residual.
// A = pw [o][c] swizzled LDS, B = a [l][c] swizzled LDS (from bf16 abuf).
// grid (32 lt, 8 b), block 256 (4 waves).
// ---------------------------------------------------------------------------
__global__ __launch_bounds__(256) void k_proj(const float* __restrict__ x,
                                              const unsigned short* __restrict__ abuf,
                                              const float* __restrict__ pw,
                                              const float* __restrict__ pb,
                                              float* __restrict__ out) {
    int lt = blockIdx.x;   // 0..31
    int b  = blockIdx.y;   // 0..7
    int tid = threadIdx.x;
    int l0 = lt * 64;
    __shared__ unsigned short as_[64 * 64];  // [l][c] swizzled
    __shared__ unsigned short ws[64 * 64];   // [o][c] swizzled

#pragma unroll
    for (int k = 0; k < 2; k++) {
        int chunk = tid + k * 256;           // 0..511
        int c = chunk >> 3, l8 = chunk & 7;
        uint4 v8 = *(const uint4*)(abuf + (size_t)(b * 64 + c) * LL + l0 + l8 * 8);
        const unsigned short* sp = (const unsigned short*)&v8;
#pragma unroll
        for (int j = 0; j < 8; j++) {
            int l = l8 * 8 + j;
            as_[l * 64 + (c ^ ((l & 7) << 3))] = sp[j];
        }
    }
#pragma unroll
    for (int k = 0; k < 4; k++) {
        int chunk = tid + k * 256;
        int o = chunk >> 4, c4 = chunk & 15;
        f32x4 wv4 = *(const f32x4*)(pw + (size_t)o * 64 + c4 * 4);
        uint2 pw2 = make_uint2(pack2(wv4[0], wv4[1]), pack2(wv4[2], wv4[3]));
        *(uint2*)&ws[o * 64 + ((c4 * 4) ^ ((o & 7) << 3))] = pw2;
    }
    __syncthreads();

    int wv_ = tid >> 6, lane = tid & 63, hi = lane >> 5, tl = lane & 31;
    int o0 = (wv_ & 1) * 32, lw = (wv_ >> 1) * 32;
    int arow = o0 + tl, brow = lw + tl;
    f32x16 acc = {};
#pragma unroll
    for (int kk = 0; kk < 4; kk++) {
        int cb = kk * 16 + hi * 8;
        short8 af = *(const short8*)&ws[arow * 64 + (cb ^ ((arow & 7) << 3))];
        short8 bf = *(const short8*)&as_[brow * 64 + (cb ^ ((brow & 7) << 3))];
        acc = __builtin_amdgcn_mfma_f32_32x32x16_bf16(af, bf, acc, 0, 0, 0);
    }

    int l = l0 + lw + tl;
#pragma unroll
    for (int r = 0; r < 16; r++) {
        int o = o0 + (r & 3) + 8 * (r >> 2) + 4 * hi;
        size_t idx = (size_t)(b * 64 + o) * LL + l;
        out[idx] = x[idx] + acc[r] + pb[o];
    }
}

// ---------------------------------------------------------------------------
extern "C" void kernel_launch(void* const* d_in, const int* in_sizes, int n_in,
                              void* d_out, int out_size, void* d_ws, size_t ws_size,
                              hipStream_t stream) {
    const float* x   = (const float*)d_in[0];
    const float* gnw = (const float*)d_in[1];
    const float* gnb = (const float*)d_in[2];
    const float* qw  = (const float*)d_in[3];
    const float* qb  = (const float*)d_in[4];
    const float* pw  = (const float*)d_in[5];
    const float* pb  = (const float*)d_in[6];
    float* out = (float*)d_out;

    float* wsf   = (float*)d_ws;
    float* stats = wsf;                                  // 64 floats (raw sums)
    unsigned short* qt = (unsigned short*)(wsf + 64);    // 32*2048*16 bf16
    unsigned short* kt = qt + (size_t)32 * LL * 16;
    unsigned short* vb = kt + (size_t)32 * LL * 16;
    unsigned short* abuf = vb + (size_t)32 * LL * 16;    // 8*64*2048 bf16

    hipMemsetAsync(stats, 0, 64 * sizeof(float), stream);
    hipLaunchKernelGGL(k_gnstats, dim3(128), dim3(256), 0, stream, x, stats);
    hipLaunchKernelGGL(k_qkv, dim3(32, 3, 8), dim3(256), 0, stream,
                       x, gnw, gnb, qw, qb, stats, qt, kt, vb);
    hipLaunchKernelGGL(k_attn, dim3(64, 32), dim3(256), 0, stream, qt, kt, vb, abuf);
    hipLaunchKernelGGL(k_proj, dim3(32, 8), dim3(256), 0, stream,
                       x, abuf, pw, pb, out);
}

// Round 6
// 124.851 us; speedup vs baseline: 4.6907x; 1.0067x over previous
//
#include <hip/hip_runtime.h>
#include <hip/hip_bf16.h>

#define LL 2048

typedef float f32x16 __attribute__((ext_vector_type(16)));
typedef float f32x4 __attribute__((ext_vector_type(4)));
typedef short short8 __attribute__((ext_vector_type(8)));

__device__ __forceinline__ float exp2_fast(float x) {
    float r;
    asm volatile("v_exp_f32 %0, %1" : "=v"(r) : "v"(x));
    return r;
}

__device__ __forceinline__ uint32_t pack2(float a, float b) {
    union { __hip_bfloat16 h; unsigned short s; } ua, ub;
    ua.h = __float2bfloat16(a);
    ub.h = __float2bfloat16(b);
    return (uint32_t)ua.s | ((uint32_t)ub.s << 16);
}

__device__ __forceinline__ unsigned short bf16of(float a) {
    union { __hip_bfloat16 h; unsigned short s; } u;
    u.h = __float2bfloat16(a);
    return u.s;
}

// v_permlane32_swap_b32 D, S:  D_row1 <- S_row0_old ; S_row0 <- D_row1_old.
// (D lanes 0-31 and S lanes 32-63 unchanged.)
__device__ __forceinline__ void permswap(uint32_t& d, uint32_t& s) {
    asm("v_permlane32_swap_b32 %0, %1" : "+v"(d), "+v"(s));
}

// ---------------------------------------------------------------------------
// Kernel 1: GroupNorm partial sums. 4 blocks per (b,g); each block writes its
// own (sum, sumsq) pair -- no memset, no atomics. stats[128*2].
// ---------------------------------------------------------------------------
__global__ __launch_bounds__(256) void k_gnstats(const float* __restrict__ x,
                                                 float* __restrict__ stats) {
    int bg = blockIdx.x >> 2, part = blockIdx.x & 3;
    const f32x4* p = (const f32x4*)(x + (size_t)bg * (16 * LL)) + part * 2048;
    float s1 = 0.f, s2 = 0.f;
    for (int i = threadIdx.x; i < 2048; i += 256) {
        f32x4 v = p[i];
        s1 += v[0] + v[1] + v[2] + v[3];
        s2 += v[0] * v[0] + v[1] * v[1] + v[2] * v[2] + v[3] * v[3];
    }
#pragma unroll
    for (int off = 32; off > 0; off >>= 1) {
        s1 += __shfl_down(s1, off, 64);
        s2 += __shfl_down(s2, off, 64);
    }
    __shared__ float r1[4], r2[4];
    int lane = threadIdx.x & 63, wv = threadIdx.x >> 6;
    if (lane == 0) { r1[wv] = s1; r2[wv] = s2; }
    __syncthreads();
    if (threadIdx.x == 0) {
        stats[blockIdx.x * 2]     = r1[0] + r1[1] + r1[2] + r1[3];
        stats[blockIdx.x * 2 + 1] = r2[0] + r2[1] + r2[2] + r2[3];
    }
}

// ---------------------------------------------------------------------------
// Kernel 2: QKV conv1x1 as bf16 MFMA GEMM with fused GroupNorm (partials
// combined inline). Outputs: qt [bh][t][16c] (*0.5),
// kt [bh][s][16c] (*0.5*log2e), vb [bh][16c][s].
// grid (32 lt, 3 ot, 8 b), block 256 (4 waves: 2 o-tiles x 2 l-tiles).
// ---------------------------------------------------------------------------
__global__ __launch_bounds__(256) void k_qkv(const float* __restrict__ x,
                                             const float* __restrict__ gnw,
                                             const float* __restrict__ gnb,
                                             const float* __restrict__ qw,
                                             const float* __restrict__ qb,
                                             const float* __restrict__ stats,
                                             unsigned short* __restrict__ qt,
                                             unsigned short* __restrict__ kt,
                                             unsigned short* __restrict__ vb) {
    int lt = blockIdx.x;   // 0..31
    int ot = blockIdx.y;   // 0..2  (q, k, v)
    int b  = blockIdx.z;   // 0..7
    int tid = threadIdx.x;
    int l0 = lt * 64;
    __shared__ unsigned short xs[64 * 64];   // [l][c], short idx c ^ ((l&7)<<3)
    __shared__ unsigned short ws[64 * 64];   // [o][c], short idx c ^ ((o&7)<<3)

#pragma unroll
    for (int k = 0; k < 4; k++) {
        int chunk = tid + k * 256;        // 0..1023
        int c = chunk >> 4, l4 = chunk & 15;
        f32x4 v = *(const f32x4*)(x + ((size_t)b * 64 + c) * LL + l0 + l4 * 4);
        int g = c >> 4;
        int sb = (b * 4 + g) * 8;         // 4 partial (s1,s2) pairs
        float s1 = stats[sb] + stats[sb + 2] + stats[sb + 4] + stats[sb + 6];
        float s2 = stats[sb + 1] + stats[sb + 3] + stats[sb + 5] + stats[sb + 7];
        float mean = s1 * (1.0f / 32768.0f);
        float var  = s2 * (1.0f / 32768.0f) - mean * mean;
        float rstd = rsqrtf(var + 1e-5f);
        float wgt = gnw[c] * rstd;
        float bia = gnb[c] - mean * wgt;
#pragma unroll
        for (int j = 0; j < 4; j++) {
            int l = l4 * 4 + j;
            xs[l * 64 + (c ^ ((l & 7) << 3))] = bf16of(v[j] * wgt + bia);
        }
        // weight tile
        int o = c, c4 = l4;
        f32x4 wv4 = *(const f32x4*)(qw + (size_t)(ot * 64 + o) * 64 + c4 * 4);
        uint2 pw2 = make_uint2(pack2(wv4[0], wv4[1]), pack2(wv4[2], wv4[3]));
        *(uint2*)&ws[o * 64 + ((c4 * 4) ^ ((o & 7) << 3))] = pw2;
    }
    __syncthreads();

    int wv_ = tid >> 6, lane = tid & 63, hi = lane >> 5, tl = lane & 31;
    int o0 = (wv_ & 1) * 32, lw = (wv_ >> 1) * 32;
    int arow = o0 + tl, brow = lw + tl;
    f32x16 acc = {};
#pragma unroll
    for (int kk = 0; kk < 4; kk++) {
        int cb = kk * 16 + hi * 8;   // short offset of k-chunk
        short8 af = *(const short8*)&ws[arow * 64 + (cb ^ ((arow & 7) << 3))];
        short8 bf = *(const short8*)&xs[brow * 64 + (cb ^ ((brow & 7) << 3))];
        acc = __builtin_amdgcn_mfma_f32_32x32x16_bf16(af, bf, acc, 0, 0, 0);
    }

    int t = l0 + lw + tl;            // global l (column) for this lane
    if (ot < 2) {
        float sc = ot ? 0.72134752f : 0.5f;   // k also carries log2(e)
        unsigned short* base = (ot ? kt : qt) + (size_t)(b * 4) * (LL * 16);
#pragma unroll
        for (int g = 0; g < 4; g++) {
            int ob = o0 + 8 * g + 4 * hi;     // 4 consecutive o from here
            float v0 = (acc[4 * g]     + qb[ot * 64 + ob])     * sc;
            float v1 = (acc[4 * g + 1] + qb[ot * 64 + ob + 1]) * sc;
            float v2 = (acc[4 * g + 2] + qb[ot * 64 + ob + 2]) * sc;
            float v3 = (acc[4 * g + 3] + qb[ot * 64 + ob + 3]) * sc;
            uint2 pkv = make_uint2(pack2(v0, v1), pack2(v2, v3));
            *(uint2*)(base + (size_t)(ob >> 4) * (LL * 16) + (size_t)t * 16 + (ob & 15)) = pkv;
        }
    } else {
        unsigned short* base = vb + (size_t)(b * 4) * (16 * LL);
#pragma unroll
        for (int r = 0; r < 16; r++) {
            int o = o0 + (r & 3) + 8 * (r >> 2) + 4 * hi;
            base[(size_t)(o >> 4) * (16 * LL) + (size_t)(o & 15) * LL + t] =
                bf16of(acc[r] + qb[128 + o]);
        }
    }
}

// ---------------------------------------------------------------------------
// Kernel 3: MFMA flash attention, fixed-max (m=0) softmax, split-K x4.
// p = exp2(score) directly (exact in f32; |score_log2| bounded << 110).
// P->A-fragment repack via v_permlane32_swap_b32: one swap(pk0,pk2) yields
// BOTH fragment words (lo/hi halves verified against the R2/R3 shfl path).
// Output bf16 abuf [b*64+c][t]. grid (64 t-tiles, 32 bh), block 256.
// ---------------------------------------------------------------------------
__global__ __launch_bounds__(256) void k_attn(const unsigned short* __restrict__ qt,
                                              const unsigned short* __restrict__ kt,
                                              const unsigned short* __restrict__ vb,
                                              unsigned short* __restrict__ abuf) {
    int wv = threadIdx.x >> 6;          // split index 0..3
    int lane = threadIdx.x & 63;
    int hi = lane >> 5, tlo = lane & 31;
    int bh = blockIdx.y;
    int t0 = blockIdx.x * 32;

    __shared__ float lds_d2[3][32][17];
    __shared__ float lds_l[3][32];

    const unsigned short* qp = qt + (size_t)bh * (LL * 16);
    const unsigned short* kp = kt + (size_t)bh * (LL * 16);
    const unsigned short* vp = vb + (size_t)bh * (16 * LL) + (size_t)(tlo & 15) * LL;

    short8 qf = *(const short8*)(qp + (size_t)(t0 + tlo) * 16 + 8 * hi);

    f32x16 d2 = {};
    float lsum = 0.f;

    int sbeg = wv * 512;
    for (int s0 = sbeg; s0 < sbeg + 512; s0 += 32) {
        short8 kf  = *(const short8*)(kp + (size_t)(s0 + tlo) * 16 + 8 * hi);
        short8 vf0 = *(const short8*)(vp + s0 + 8 * hi);
        short8 vf1 = *(const short8*)(vp + s0 + 16 + 8 * hi);

        f32x16 z = {};
        f32x16 d1 = __builtin_amdgcn_mfma_f32_32x32x16_bf16(kf, qf, z, 0, 0, 0);

        float p[16], ps = 0.f;
#pragma unroll
        for (int r = 0; r < 16; r++) { p[r] = exp2_fast(d1[r]); ps += p[r]; }
        lsum += ps;

        uint32_t pk[8];
#pragma unroll
        for (int i = 0; i < 8; i++) pk[i] = pack2(p[2 * i], p[2 * i + 1]);

        // A1.u[0]=pk0: lo=own pk0, hi=partner pk2 ; A1.u[2]=pk2: lo=partner
        // pk0, hi=own pk2  -- one permlane32_swap produces both words.
        permswap(pk[0], pk[2]);
        permswap(pk[1], pk[3]);
        permswap(pk[4], pk[6]);
        permswap(pk[5], pk[7]);
        union { uint32_t u[4]; short8 s; } A1, A2;
        A1.u[0] = pk[0]; A1.u[1] = pk[1]; A1.u[2] = pk[2]; A1.u[3] = pk[3];
        A2.u[0] = pk[4]; A2.u[1] = pk[5]; A2.u[2] = pk[6]; A2.u[3] = pk[7];

        d2 = __builtin_amdgcn_mfma_f32_32x32x16_bf16(A1.s, vf0, d2, 0, 0, 0);
        d2 = __builtin_amdgcn_mfma_f32_32x32x16_bf16(A2.s, vf1, d2, 0, 0, 0);
    }

    float ls = lsum + __shfl_xor(lsum, 32, 64);   // total partial-l for t=tlo

    if (wv > 0) {
        int w = wv - 1;
#pragma unroll
        for (int r = 0; r < 16; r++) {
            int row = (r & 3) + 8 * (r >> 2) + 4 * hi;
            if (tlo < 16) lds_d2[w][row][tlo] = d2[r];
        }
        if (hi == 0) lds_l[w][tlo] = ls;
    }
    __syncthreads();
    if (wv == 0) {
        float lall = ls + lds_l[0][tlo] + lds_l[1][tlo] + lds_l[2][tlo];
        float rl = 1.0f / lall;                   // reciprocal for own t
        int tc = tlo & 15;
        unsigned short* op = abuf + ((size_t)bh * 16 + tlo) * LL + t0;
        float v[16];
#pragma unroll
        for (int r = 0; r < 16; r++) {            // all lanes run (shfl)
            int row = (r & 3) + 8 * (r >> 2) + 4 * hi;
            float osum = d2[r] + lds_d2[0][row][tc]
                       + lds_d2[1][row][tc] + lds_d2[2][row][tc];
            v[r] = osum * __shfl(rl, row, 64);
        }
        if (tlo < 16) {
#pragma unroll
            for (int g = 0; g < 4; g++) {
                uint2 pkv = make_uint2(pack2(v[4 * g], v[4 * g + 1]),
                                       pack2(v[4 * g + 2], v[4 * g + 3]));
                *(uint2*)(op + 8 * g + 4 * hi) = pkv;
            }
        }
    }
}

// ---------------------------------------------------------------------------
// Kernel 4: proj conv1x1 as bf16 MFMA GEMM + bias + fp32 residual.
// A = pw [o][c] swizzled LDS, B = a [l][c] swizzled LDS (from bf16 abuf).
// grid (32 lt, 8 b), block 256 (4 waves).
// ---------------------------------------------------------------------------
__global__ __launch_bounds__(256) void k_proj(const float* __restrict__ x,
                                              const unsigned short* __restrict__ abuf,
                                              const float* __restrict__ pw,
                                              const float* __restrict__ pb,
                                              float* __restrict__ out) {
    int lt = blockIdx.x;   // 0..31
    int b  = blockIdx.y;   // 0..7
    int tid = threadIdx.x;
    int l0 = lt * 64;
    __shared__ unsigned short as_[64 * 64];  // [l][c] swizzled
    __shared__ unsigned short ws[64 * 64];   // [o][c] swizzled

#pragma unroll
    for (int k = 0; k < 2; k++) {
        int chunk = tid + k * 256;           // 0..511
        int c = chunk >> 3, l8 = chunk & 7;
        uint4 v8 = *(const uint4*)(abuf + (size_t)(b * 64 + c) * LL + l0 + l8 * 8);
        const unsigned short* sp = (const unsigned short*)&v8;
#pragma unroll
        for (int j = 0; j < 8; j++) {
            int l = l8 * 8 + j;
            as_[l * 64 + (c ^ ((l & 7) << 3))] = sp[j];
        }
    }
#pragma unroll
    for (int k = 0; k < 4; k++) {
        int chunk = tid + k * 256;
        int o = chunk >> 4, c4 = chunk & 15;
        f32x4 wv4 = *(const f32x4*)(pw + (size_t)o * 64 + c4 * 4);
        uint2 pw2 = make_uint2(pack2(wv4[0], wv4[1]), pack2(wv4[2], wv4[3]));
        *(uint2*)&ws[o * 64 + ((c4 * 4) ^ ((o & 7) << 3))] = pw2;
    }
    __syncthreads();

    int wv_ = tid >> 6, lane = tid & 63, hi = lane >> 5, tl = lane & 31;
    int o0 = (wv_ & 1) * 32, lw = (wv_ >> 1) * 32;
    int arow = o0 + tl, brow = lw + tl;
    f32x16 acc = {};
#pragma unroll
    for (int kk = 0; kk < 4; kk++) {
        int cb = kk * 16 + hi * 8;
        short8 af = *(const short8*)&ws[arow * 64 + (cb ^ ((arow & 7) << 3))];
        short8 bf = *(const short8*)&as_[brow * 64 + (cb ^ ((brow & 7) << 3))];
        acc = __builtin_amdgcn_mfma_f32_32x32x16_bf16(af, bf, acc, 0, 0, 0);
    }

    int l = l0 + lw + tl;
#pragma unroll
    for (int r = 0; r < 16; r++) {
        int o = o0 + (r & 3) + 8 * (r >> 2) + 4 * hi;
        size_t idx = (size_t)(b * 64 + o) * LL + l;
        out[idx] = x[idx] + acc[r] + pb[o];
    }
}

// ---------------------------------------------------------------------------
extern "C" void kernel_launch(void* const* d_in, const int* in_sizes, int n_in,
                              void* d_out, int out_size, void* d_ws, size_t ws_size,
                              hipStream_t stream) {
    const float* x   = (const float*)d_in[0];
    const float* gnw = (const float*)d_in[1];
    const float* gnb = (const float*)d_in[2];
    const float* qw  = (const float*)d_in[3];
    const float* qb  = (const float*)d_in[4];
    const float* pw  = (const float*)d_in[5];
    const float* pb  = (const float*)d_in[6];
    float* out = (float*)d_out;

    float* wsf   = (float*)d_ws;
    float* stats = wsf;                                  // 256 floats (partials)
    unsigned short* qt = (unsigned short*)(wsf + 256);   // 32*2048*16 bf16
    unsigned short* kt = qt + (size_t)32 * LL * 16;
    unsigned short* vb = kt + (size_t)32 * LL * 16;
    unsigned short* abuf = vb + (size_t)32 * LL * 16;    // 8*64*2048 bf16

    hipLaunchKernelGGL(k_gnstats, dim3(128), dim3(256), 0, stream, x, stats);
    hipLaunchKernelGGL(k_qkv, dim3(32, 3, 8), dim3(256), 0, stream,
                       x, gnw, gnb, qw, qb, stats, qt, kt, vb);
    hipLaunchKernelGGL(k_attn, dim3(64, 32), dim3(256), 0, stream, qt, kt, vb, abuf);
    hipLaunchKernelGGL(k_proj, dim3(32, 8), dim3(256), 0, stream,
                       x, abuf, pw, pb, out);
}

// Round 7
// 121.213 us; speedup vs baseline: 4.8315x; 1.0300x over previous
//
#include <hip/hip_runtime.h>
#include <hip/hip_bf16.h>

#define LL 2048

typedef float f32x16 __attribute__((ext_vector_type(16)));
typedef float f32x4 __attribute__((ext_vector_type(4)));
typedef short short8 __attribute__((ext_vector_type(8)));

__device__ __forceinline__ float exp2_fast(float x) {
    float r;
    asm volatile("v_exp_f32 %0, %1" : "=v"(r) : "v"(x));
    return r;
}

__device__ __forceinline__ uint32_t pack2(float a, float b) {
    union { __hip_bfloat16 h; unsigned short s; } ua, ub;
    ua.h = __float2bfloat16(a);
    ub.h = __float2bfloat16(b);
    return (uint32_t)ua.s | ((uint32_t)ub.s << 16);
}

__device__ __forceinline__ unsigned short bf16of(float a) {
    union { __hip_bfloat16 h; unsigned short s; } u;
    u.h = __float2bfloat16(a);
    return u.s;
}

// v_permlane32_swap_b32 D, S:  D_row1 <- S_row0_old ; S_row0 <- D_row1_old.
__device__ __forceinline__ void permswap(uint32_t& d, uint32_t& s) {
    asm("v_permlane32_swap_b32 %0, %1" : "+v"(d), "+v"(s));
}

// ---------------------------------------------------------------------------
// Kernel 1: GroupNorm partial sums (4 blocks per (b,g), partials to distinct
// slots) + block 0 fills the bf16 ones-buffer used by k_attn's lsum trick.
// ---------------------------------------------------------------------------
__global__ __launch_bounds__(256) void k_gnstats(const float* __restrict__ x,
                                                 float* __restrict__ stats,
                                                 unsigned short* __restrict__ ones) {
    if (blockIdx.x == 0) {
        uint4 v = make_uint4(0x3F803F80u, 0x3F803F80u, 0x3F803F80u, 0x3F803F80u);
        *(uint4*)(ones + threadIdx.x * 16)     = v;
        *(uint4*)(ones + threadIdx.x * 16 + 8) = v;
    }
    int bg = blockIdx.x >> 2, part = blockIdx.x & 3;
    const f32x4* p = (const f32x4*)(x + (size_t)bg * (16 * LL)) + part * 2048;
    float s1 = 0.f, s2 = 0.f;
    for (int i = threadIdx.x; i < 2048; i += 256) {
        f32x4 v = p[i];
        s1 += v[0] + v[1] + v[2] + v[3];
        s2 += v[0] * v[0] + v[1] * v[1] + v[2] * v[2] + v[3] * v[3];
    }
#pragma unroll
    for (int off = 32; off > 0; off >>= 1) {
        s1 += __shfl_down(s1, off, 64);
        s2 += __shfl_down(s2, off, 64);
    }
    __shared__ float r1[4], r2[4];
    int lane = threadIdx.x & 63, wv = threadIdx.x >> 6;
    if (lane == 0) { r1[wv] = s1; r2[wv] = s2; }
    __syncthreads();
    if (threadIdx.x == 0) {
        stats[blockIdx.x * 2]     = r1[0] + r1[1] + r1[2] + r1[3];
        stats[blockIdx.x * 2 + 1] = r2[0] + r2[1] + r2[2] + r2[3];
    }
}

// ---------------------------------------------------------------------------
// Kernel 2: QKV conv1x1 as bf16 MFMA GEMM with fused GroupNorm.
// Per-channel (wgt,bia) computed ONCE into LDS (kills per-thread stats-load
// storm); x staged 4ch x 4pos per thread with ds_write_b64.
// Outputs: qt [bh][t][16c] (*0.5), kt [bh][s][16c] (*0.5*log2e),
//          vb [bh][16c][s].  grid (32 lt, 3 ot, 8 b), block 256.
// ---------------------------------------------------------------------------
__global__ __launch_bounds__(256) void k_qkv(const float* __restrict__ x,
                                             const float* __restrict__ gnw,
                                             const float* __restrict__ gnb,
                                             const float* __restrict__ qw,
                                             const float* __restrict__ qb,
                                             const float* __restrict__ stats,
                                             unsigned short* __restrict__ qt,
                                             unsigned short* __restrict__ kt,
                                             unsigned short* __restrict__ vb) {
    int lt = blockIdx.x;   // 0..31
    int ot = blockIdx.y;   // 0..2  (q, k, v)
    int b  = blockIdx.z;   // 0..7
    int tid = threadIdx.x;
    int l0 = lt * 64;
    __shared__ unsigned short xs[64 * 64];   // [l][c], short idx c ^ ((l&7)<<3)
    __shared__ unsigned short ws[64 * 64];   // [o][c], short idx c ^ ((o&7)<<3)
    __shared__ float wb[64][2];              // per-channel wgt, bia

    if (tid < 64) {
        int c = tid, g = c >> 4;
        int sb = (b * 4 + g) * 8;
        float s1 = stats[sb] + stats[sb + 2] + stats[sb + 4] + stats[sb + 6];
        float s2 = stats[sb + 1] + stats[sb + 3] + stats[sb + 5] + stats[sb + 7];
        float mean = s1 * (1.0f / 32768.0f);
        float var  = s2 * (1.0f / 32768.0f) - mean * mean;
        float rstd = rsqrtf(var + 1e-5f);
        float wgt = gnw[c] * rstd;
        wb[c][0] = wgt;
        wb[c][1] = gnb[c] - mean * wgt;
    }
    // weight tile staging (independent of wb)
#pragma unroll
    for (int k = 0; k < 4; k++) {
        int chunk = tid + k * 256;
        int o = chunk >> 4, c4 = chunk & 15;
        f32x4 wv4 = *(const f32x4*)(qw + (size_t)(ot * 64 + o) * 64 + c4 * 4);
        uint2 pw2 = make_uint2(pack2(wv4[0], wv4[1]), pack2(wv4[2], wv4[3]));
        *(uint2*)&ws[o * 64 + ((c4 * 4) ^ ((o & 7) << 3))] = pw2;
    }
    __syncthreads();   // wb ready

    // x staging: thread = (c-quad, l4-group)
    {
        int cq = tid >> 4, l4 = tid & 15, c0 = cq * 4;
        f32x4 xv0 = *(const f32x4*)(x + ((size_t)b * 64 + c0)     * LL + l0 + l4 * 4);
        f32x4 xv1 = *(const f32x4*)(x + ((size_t)b * 64 + c0 + 1) * LL + l0 + l4 * 4);
        f32x4 xv2 = *(const f32x4*)(x + ((size_t)b * 64 + c0 + 2) * LL + l0 + l4 * 4);
        f32x4 xv3 = *(const f32x4*)(x + ((size_t)b * 64 + c0 + 3) * LL + l0 + l4 * 4);
        float w0 = wb[c0][0], b0 = wb[c0][1];
        float w1 = wb[c0 + 1][0], b1 = wb[c0 + 1][1];
        float w2 = wb[c0 + 2][0], b2 = wb[c0 + 2][1];
        float w3 = wb[c0 + 3][0], b3 = wb[c0 + 3][1];
#pragma unroll
        for (int j = 0; j < 4; j++) {
            int l = l4 * 4 + j;
            uint32_t lo = pack2(xv0[j] * w0 + b0, xv1[j] * w1 + b1);
            uint32_t hw = pack2(xv2[j] * w2 + b2, xv3[j] * w3 + b3);
            *(uint2*)&xs[l * 64 + (c0 ^ ((l & 7) << 3))] = make_uint2(lo, hw);
        }
    }
    __syncthreads();

    int wv_ = tid >> 6, lane = tid & 63, hi = lane >> 5, tl = lane & 31;
    int o0 = (wv_ & 1) * 32, lw = (wv_ >> 1) * 32;
    int arow = o0 + tl, brow = lw + tl;
    f32x16 acc = {};
#pragma unroll
    for (int kk = 0; kk < 4; kk++) {
        int cb = kk * 16 + hi * 8;
        short8 af = *(const short8*)&ws[arow * 64 + (cb ^ ((arow & 7) << 3))];
        short8 bf = *(const short8*)&xs[brow * 64 + (cb ^ ((brow & 7) << 3))];
        acc = __builtin_amdgcn_mfma_f32_32x32x16_bf16(af, bf, acc, 0, 0, 0);
    }

    int t = l0 + lw + tl;
    if (ot < 2) {
        float sc = ot ? 0.72134752f : 0.5f;   // k also carries log2(e)
        unsigned short* base = (ot ? kt : qt) + (size_t)(b * 4) * (LL * 16);
#pragma unroll
        for (int g = 0; g < 4; g++) {
            int ob = o0 + 8 * g + 4 * hi;
            float v0 = (acc[4 * g]     + qb[ot * 64 + ob])     * sc;
            float v1 = (acc[4 * g + 1] + qb[ot * 64 + ob + 1]) * sc;
            float v2 = (acc[4 * g + 2] + qb[ot * 64 + ob + 2]) * sc;
            float v3 = (acc[4 * g + 3] + qb[ot * 64 + ob + 3]) * sc;
            uint2 pkv = make_uint2(pack2(v0, v1), pack2(v2, v3));
            *(uint2*)(base + (size_t)(ob >> 4) * (LL * 16) + (size_t)t * 16 + (ob & 15)) = pkv;
        }
    } else {
        unsigned short* base = vb + (size_t)(b * 4) * (16 * LL);
#pragma unroll
        for (int r = 0; r < 16; r++) {
            int o = o0 + (r & 3) + 8 * (r >> 2) + 4 * hi;
            base[(size_t)(o >> 4) * (16 * LL) + (size_t)(o & 15) * LL + t] =
                bf16of(acc[r] + qb[128 + o]);
        }
    }
}

// ---------------------------------------------------------------------------
// Kernel 3: MFMA flash attention, fixed-max softmax, split-K x4.
// PV B-operand cols 16-31 = ONES -> d2 cols 16-31 accumulate the row sums
// (lsum) for free on the MFMA pipe. K/V register prefetch one tile ahead.
// grid (64 t-tiles, 32 bh), block 256.
// ---------------------------------------------------------------------------
__global__ __launch_bounds__(256) void k_attn(const unsigned short* __restrict__ qt,
                                              const unsigned short* __restrict__ kt,
                                              const unsigned short* __restrict__ vb,
                                              const unsigned short* __restrict__ ones,
                                              unsigned short* __restrict__ abuf) {
    int wv = threadIdx.x >> 6;          // split index 0..3
    int lane = threadIdx.x & 63;
    int hi = lane >> 5, tlo = lane & 31;
    int bh = blockIdx.y;
    int t0 = blockIdx.x * 32;

    __shared__ float lds_d2[3][32][33];

    const unsigned short* qp = qt + (size_t)bh * (LL * 16);
    const unsigned short* kp = kt + (size_t)bh * (LL * 16);
    const unsigned short* vp = (tlo < 16)
        ? vb + (size_t)bh * (16 * LL) + (size_t)tlo * LL
        : ones;                          // lanes 16-31 feed 1.0 -> lsum cols

    short8 qf = *(const short8*)(qp + (size_t)(t0 + tlo) * 16 + 8 * hi);

    f32x16 d2 = {};

    int sbeg = wv * 512, send = sbeg + 512;
    short8 kf  = *(const short8*)(kp + (size_t)(sbeg + tlo) * 16 + 8 * hi);
    short8 vf0 = *(const short8*)(vp + sbeg + 8 * hi);
    short8 vf1 = *(const short8*)(vp + sbeg + 16 + 8 * hi);

    for (int s0 = sbeg; s0 < send; s0 += 32) {
        int sn = (s0 + 32 < send) ? s0 + 32 : sbeg;   // prefetch next tile
        short8 kn  = *(const short8*)(kp + (size_t)(sn + tlo) * 16 + 8 * hi);
        short8 vn0 = *(const short8*)(vp + sn + 8 * hi);
        short8 vn1 = *(const short8*)(vp + sn + 16 + 8 * hi);

        f32x16 z = {};
        f32x16 d1 = __builtin_amdgcn_mfma_f32_32x32x16_bf16(kf, qf, z, 0, 0, 0);

        float p[16];
#pragma unroll
        for (int r = 0; r < 16; r++) p[r] = exp2_fast(d1[r]);

        uint32_t pk[8];
#pragma unroll
        for (int i = 0; i < 8; i++) pk[i] = pack2(p[2 * i], p[2 * i + 1]);

        permswap(pk[0], pk[2]);
        permswap(pk[1], pk[3]);
        permswap(pk[4], pk[6]);
        permswap(pk[5], pk[7]);
        union { uint32_t u[4]; short8 s; } A1, A2;
        A1.u[0] = pk[0]; A1.u[1] = pk[1]; A1.u[2] = pk[2]; A1.u[3] = pk[3];
        A2.u[0] = pk[4]; A2.u[1] = pk[5]; A2.u[2] = pk[6]; A2.u[3] = pk[7];

        d2 = __builtin_amdgcn_mfma_f32_32x32x16_bf16(A1.s, vf0, d2, 0, 0, 0);
        d2 = __builtin_amdgcn_mfma_f32_32x32x16_bf16(A2.s, vf1, d2, 0, 0, 0);

        kf = kn; vf0 = vn0; vf1 = vn1;
    }

    if (wv > 0) {
        int w = wv - 1;
#pragma unroll
        for (int r = 0; r < 16; r++) {
            int row = (r & 3) + 8 * (r >> 2) + 4 * hi;
            lds_d2[w][row][tlo] = d2[r];   // O cols 0-15, lsum cols 16-31
        }
    }
    __syncthreads();
    if (wv == 0) {
        unsigned short* op = abuf + ((size_t)bh * 16 + tlo) * LL + t0;
        float v[16];
#pragma unroll
        for (int r = 0; r < 16; r++) {
            int row = (r & 3) + 8 * (r >> 2) + 4 * hi;
            float osum = d2[r] + lds_d2[0][row][tlo]
                       + lds_d2[1][row][tlo] + lds_d2[2][row][tlo];
            float rv = 1.0f / osum;              // meaningful on lanes 16-31
            float rl = __shfl_xor(rv, 16, 64);   // O-lanes fetch rcp(lsum)
            v[r] = osum * rl;
        }
        if (tlo < 16) {
#pragma unroll
            for (int g = 0; g < 4; g++) {
                uint2 pkv = make_uint2(pack2(v[4 * g], v[4 * g + 1]),
                                       pack2(v[4 * g + 2], v[4 * g + 3]));
                *(uint2*)(op + 8 * g + 4 * hi) = pkv;
            }
        }
    }
}

// ---------------------------------------------------------------------------
// Kernel 4: proj conv1x1 as bf16 MFMA GEMM + bias + fp32 residual.
// abuf staged 4ch x 4pos per thread with ds_write_b64.
// grid (32 lt, 8 b), block 256 (4 waves).
// ---------------------------------------------------------------------------
__global__ __launch_bounds__(256) void k_proj(const float* __restrict__ x,
                                              const unsigned short* __restrict__ abuf,
                                              const float* __restrict__ pw,
                                              const float* __restrict__ pb,
                                              float* __restrict__ out) {
    int lt = blockIdx.x;   // 0..31
    int b  = blockIdx.y;   // 0..7
    int tid = threadIdx.x;
    int l0 = lt * 64;
    __shared__ unsigned short as_[64 * 64];  // [l][c] swizzled
    __shared__ unsigned short ws[64 * 64];   // [o][c] swizzled

    {
        int cq = tid >> 4, t4 = tid & 15, c0 = cq * 4;
        uint2 ld0 = *(const uint2*)(abuf + (size_t)(b * 64 + c0)     * LL + l0 + t4 * 4);
        uint2 ld1 = *(const uint2*)(abuf + (size_t)(b * 64 + c0 + 1) * LL + l0 + t4 * 4);
        uint2 ld2 = *(const uint2*)(abuf + (size_t)(b * 64 + c0 + 2) * LL + l0 + t4 * 4);
        uint2 ld3 = *(const uint2*)(abuf + (size_t)(b * 64 + c0 + 3) * LL + l0 + t4 * 4);
        const unsigned short* s0 = (const unsigned short*)&ld0;
        const unsigned short* s1 = (const unsigned short*)&ld1;
        const unsigned short* s2 = (const unsigned short*)&ld2;
        const unsigned short* s3 = (const unsigned short*)&ld3;
#pragma unroll
        for (int j = 0; j < 4; j++) {
            int l = t4 * 4 + j;
            uint32_t lo = (uint32_t)s0[j] | ((uint32_t)s1[j] << 16);
            uint32_t hw = (uint32_t)s2[j] | ((uint32_t)s3[j] << 16);
            *(uint2*)&as_[l * 64 + (c0 ^ ((l & 7) << 3))] = make_uint2(lo, hw);
        }
    }
#pragma unroll
    for (int k = 0; k < 4; k++) {
        int chunk = tid + k * 256;
        int o = chunk >> 4, c4 = chunk & 15;
        f32x4 wv4 = *(const f32x4*)(pw + (size_t)o * 64 + c4 * 4);
        uint2 pw2 = make_uint2(pack2(wv4[0], wv4[1]), pack2(wv4[2], wv4[3]));
        *(uint2*)&ws[o * 64 + ((c4 * 4) ^ ((o & 7) << 3))] = pw2;
    }
    __syncthreads();

    int wv_ = tid >> 6, lane = tid & 63, hi = lane >> 5, tl = lane & 31;
    int o0 = (wv_ & 1) * 32, lw = (wv_ >> 1) * 32;
    int arow = o0 + tl, brow = lw + tl;
    f32x16 acc = {};
#pragma unroll
    for (int kk = 0; kk < 4; kk++) {
        int cb = kk * 16 + hi * 8;
        short8 af = *(const short8*)&ws[arow * 64 + (cb ^ ((arow & 7) << 3))];
        short8 bf = *(const short8*)&as_[brow * 64 + (cb ^ ((brow & 7) << 3))];
        acc = __builtin_amdgcn_mfma_f32_32x32x16_bf16(af, bf, acc, 0, 0, 0);
    }

    int l = l0 + lw + tl;
#pragma unroll
    for (int r = 0; r < 16; r++) {
        int o = o0 + (r & 3) + 8 * (r >> 2) + 4 * hi;
        size_t idx = (size_t)(b * 64 + o) * LL + l;
        out[idx] = x[idx] + acc[r] + pb[o];
    }
}

// ---------------------------------------------------------------------------
extern "C" void kernel_launch(void* const* d_in, const int* in_sizes, int n_in,
                              void* d_out, int out_size, void* d_ws, size_t ws_size,
                              hipStream_t stream) {
    const float* x   = (const float*)d_in[0];
    const float* gnw = (const float*)d_in[1];
    const float* gnb = (const float*)d_in[2];
    const float* qw  = (const float*)d_in[3];
    const float* qb  = (const float*)d_in[4];
    const float* pw  = (const float*)d_in[5];
    const float* pb  = (const float*)d_in[6];
    float* out = (float*)d_out;

    float* wsf   = (float*)d_ws;
    float* stats = wsf;                                  // 256 floats (partials)
    unsigned short* qt = (unsigned short*)(wsf + 256);   // 32*2048*16 bf16
    unsigned short* kt = qt + (size_t)32 * LL * 16;
    unsigned short* vb = kt + (size_t)32 * LL * 16;
    unsigned short* abuf = vb + (size_t)32 * LL * 16;    // 8*64*2048 bf16
    unsigned short* ones = abuf + (size_t)8 * 64 * LL;   // 4096 bf16 of 1.0

    hipLaunchKernelGGL(k_gnstats, dim3(128), dim3(256), 0, stream, x, stats, ones);
    hipLaunchKernelGGL(k_qkv, dim3(32, 3, 8), dim3(256), 0, stream,
                       x, gnw, gnb, qw, qb, stats, qt, kt, vb);
    hipLaunchKernelGGL(k_attn, dim3(64, 32), dim3(256), 0, stream,
                       qt, kt, vb, ones, abuf);
    hipLaunchKernelGGL(k_proj, dim3(32, 8), dim3(256), 0, stream,
                       x, abuf, pw, pb, out);
}

// Round 8
// 110.967 us; speedup vs baseline: 5.2776x; 1.0923x over previous
//
#include <hip/hip_runtime.h>
#include <hip/hip_bf16.h>

#define LL 2048

typedef float f32x16 __attribute__((ext_vector_type(16)));
typedef float f32x4 __attribute__((ext_vector_type(4)));
typedef short short8 __attribute__((ext_vector_type(8)));

__device__ __forceinline__ float exp2_fast(float x) {
    float r;
    asm volatile("v_exp_f32 %0, %1" : "=v"(r) : "v"(x));
    return r;
}

__device__ __forceinline__ float rcp_fast(float x) {
    float r;
    asm("v_rcp_f32 %0, %1" : "=v"(r) : "v"(x));
    return r;
}

// HW packed conversion: D[15:0]=bf16(lo), D[31:16]=bf16(hi). 1 instr for 2.
__device__ __forceinline__ uint32_t cvtpk(float lo, float hi) {
    uint32_t r;
    asm("v_cvt_pk_bf16_f32 %0, %1, %2" : "=v"(r) : "v"(lo), "v"(hi));
    return r;
}

__device__ __forceinline__ unsigned short bf16lo(float a) {
    return (unsigned short)(cvtpk(a, a) & 0xFFFFu);
}

// v_permlane32_swap_b32 D, S:  D_row1 <- S_row0_old ; S_row0 <- D_row1_old.
__device__ __forceinline__ void permswap(uint32_t& d, uint32_t& s) {
    asm("v_permlane32_swap_b32 %0, %1" : "+v"(d), "+v"(s));
}

// ---------------------------------------------------------------------------
// Kernel 1: GroupNorm partial sums (4 blocks per (b,g), partials to distinct
// slots) + block 0 fills the bf16 ones-buffer used by k_attn's lsum trick.
// ---------------------------------------------------------------------------
__global__ __launch_bounds__(256) void k_gnstats(const float* __restrict__ x,
                                                 float* __restrict__ stats,
                                                 unsigned short* __restrict__ ones) {
    if (blockIdx.x == 0) {
        uint4 v = make_uint4(0x3F803F80u, 0x3F803F80u, 0x3F803F80u, 0x3F803F80u);
        *(uint4*)(ones + threadIdx.x * 16)     = v;
        *(uint4*)(ones + threadIdx.x * 16 + 8) = v;
    }
    int bg = blockIdx.x >> 2, part = blockIdx.x & 3;
    const f32x4* p = (const f32x4*)(x + (size_t)bg * (16 * LL)) + part * 2048;
    float s1 = 0.f, s2 = 0.f;
    for (int i = threadIdx.x; i < 2048; i += 256) {
        f32x4 v = p[i];
        s1 += v[0] + v[1] + v[2] + v[3];
        s2 += v[0] * v[0] + v[1] * v[1] + v[2] * v[2] + v[3] * v[3];
    }
#pragma unroll
    for (int off = 32; off > 0; off >>= 1) {
        s1 += __shfl_down(s1, off, 64);
        s2 += __shfl_down(s2, off, 64);
    }
    __shared__ float r1[4], r2[4];
    int lane = threadIdx.x & 63, wv = threadIdx.x >> 6;
    if (lane == 0) { r1[wv] = s1; r2[wv] = s2; }
    __syncthreads();
    if (threadIdx.x == 0) {
        stats[blockIdx.x * 2]     = r1[0] + r1[1] + r1[2] + r1[3];
        stats[blockIdx.x * 2 + 1] = r2[0] + r2[1] + r2[2] + r2[3];
    }
}

// ---------------------------------------------------------------------------
// Kernel 2: QKV conv1x1 as bf16 MFMA GEMM with fused GroupNorm.
// All f32->bf16 via v_cvt_pk_bf16_f32.
// Outputs: qt [bh][t][16c] (*0.5), kt [bh][s][16c] (*0.5*log2e),
//          vb [bh][16c][s].  grid (32 lt, 3 ot, 8 b), block 256.
// ---------------------------------------------------------------------------
__global__ __launch_bounds__(256) void k_qkv(const float* __restrict__ x,
                                             const float* __restrict__ gnw,
                                             const float* __restrict__ gnb,
                                             const float* __restrict__ qw,
                                             const float* __restrict__ qb,
                                             const float* __restrict__ stats,
                                             unsigned short* __restrict__ qt,
                                             unsigned short* __restrict__ kt,
                                             unsigned short* __restrict__ vb) {
    int lt = blockIdx.x;   // 0..31
    int ot = blockIdx.y;   // 0..2  (q, k, v)
    int b  = blockIdx.z;   // 0..7
    int tid = threadIdx.x;
    int l0 = lt * 64;
    __shared__ unsigned short xs[64 * 64];   // [l][c], short idx c ^ ((l&7)<<3)
    __shared__ unsigned short ws[64 * 64];   // [o][c], short idx c ^ ((o&7)<<3)
    __shared__ float wb[64][2];              // per-channel wgt, bia

    if (tid < 64) {
        int c = tid, g = c >> 4;
        int sb = (b * 4 + g) * 8;
        float s1 = stats[sb] + stats[sb + 2] + stats[sb + 4] + stats[sb + 6];
        float s2 = stats[sb + 1] + stats[sb + 3] + stats[sb + 5] + stats[sb + 7];
        float mean = s1 * (1.0f / 32768.0f);
        float var  = s2 * (1.0f / 32768.0f) - mean * mean;
        float rstd = rsqrtf(var + 1e-5f);
        float wgt = gnw[c] * rstd;
        wb[c][0] = wgt;
        wb[c][1] = gnb[c] - mean * wgt;
    }
    // weight tile staging (independent of wb)
#pragma unroll
    for (int k = 0; k < 4; k++) {
        int chunk = tid + k * 256;
        int o = chunk >> 4, c4 = chunk & 15;
        f32x4 wv4 = *(const f32x4*)(qw + (size_t)(ot * 64 + o) * 64 + c4 * 4);
        uint2 pw2 = make_uint2(cvtpk(wv4[0], wv4[1]), cvtpk(wv4[2], wv4[3]));
        *(uint2*)&ws[o * 64 + ((c4 * 4) ^ ((o & 7) << 3))] = pw2;
    }
    __syncthreads();   // wb ready

    // x staging: thread = (c-quad, l4-group)
    {
        int cq = tid >> 4, l4 = tid & 15, c0 = cq * 4;
        f32x4 xv0 = *(const f32x4*)(x + ((size_t)b * 64 + c0)     * LL + l0 + l4 * 4);
        f32x4 xv1 = *(const f32x4*)(x + ((size_t)b * 64 + c0 + 1) * LL + l0 + l4 * 4);
        f32x4 xv2 = *(const f32x4*)(x + ((size_t)b * 64 + c0 + 2) * LL + l0 + l4 * 4);
        f32x4 xv3 = *(const f32x4*)(x + ((size_t)b * 64 + c0 + 3) * LL + l0 + l4 * 4);
        float w0 = wb[c0][0], b0 = wb[c0][1];
        float w1 = wb[c0 + 1][0], b1 = wb[c0 + 1][1];
        float w2 = wb[c0 + 2][0], b2 = wb[c0 + 2][1];
        float w3 = wb[c0 + 3][0], b3 = wb[c0 + 3][1];
#pragma unroll
        for (int j = 0; j < 4; j++) {
            int l = l4 * 4 + j;
            uint32_t lo = cvtpk(xv0[j] * w0 + b0, xv1[j] * w1 + b1);
            uint32_t hw = cvtpk(xv2[j] * w2 + b2, xv3[j] * w3 + b3);
            *(uint2*)&xs[l * 64 + (c0 ^ ((l & 7) << 3))] = make_uint2(lo, hw);
        }
    }
    __syncthreads();

    int wv_ = tid >> 6, lane = tid & 63, hi = lane >> 5, tl = lane & 31;
    int o0 = (wv_ & 1) * 32, lw = (wv_ >> 1) * 32;
    int arow = o0 + tl, brow = lw + tl;
    f32x16 acc = {};
#pragma unroll
    for (int kk = 0; kk < 4; kk++) {
        int cb = kk * 16 + hi * 8;
        short8 af = *(const short8*)&ws[arow * 64 + (cb ^ ((arow & 7) << 3))];
        short8 bf = *(const short8*)&xs[brow * 64 + (cb ^ ((brow & 7) << 3))];
        acc = __builtin_amdgcn_mfma_f32_32x32x16_bf16(af, bf, acc, 0, 0, 0);
    }

    int t = l0 + lw + tl;
    if (ot < 2) {
        float sc = ot ? 0.72134752f : 0.5f;   // k also carries log2(e)
        unsigned short* base = (ot ? kt : qt) + (size_t)(b * 4) * (LL * 16);
#pragma unroll
        for (int g = 0; g < 4; g++) {
            int ob = o0 + 8 * g + 4 * hi;
            float v0 = (acc[4 * g]     + qb[ot * 64 + ob])     * sc;
            float v1 = (acc[4 * g + 1] + qb[ot * 64 + ob + 1]) * sc;
            float v2 = (acc[4 * g + 2] + qb[ot * 64 + ob + 2]) * sc;
            float v3 = (acc[4 * g + 3] + qb[ot * 64 + ob + 3]) * sc;
            uint2 pkv = make_uint2(cvtpk(v0, v1), cvtpk(v2, v3));
            *(uint2*)(base + (size_t)(ob >> 4) * (LL * 16) + (size_t)t * 16 + (ob & 15)) = pkv;
        }
    } else {
        unsigned short* base = vb + (size_t)(b * 4) * (16 * LL);
#pragma unroll
        for (int r = 0; r < 16; r++) {
            int o = o0 + (r & 3) + 8 * (r >> 2) + 4 * hi;
            base[(size_t)(o >> 4) * (16 * LL) + (size_t)(o & 15) * LL + t] =
                bf16lo(acc[r] + qb[128 + o]);
        }
    }
}

// ---------------------------------------------------------------------------
// Kernel 3: MFMA flash attention, fixed-max softmax, split-K x4.
// PV cols 16-31 = ones -> lsum on the MFMA pipe. Pointer-bump loop with
// unconditional next-tile prefetch (last prefetch reads adjacent mapped
// ws buffers, values unused). All conversions via v_cvt_pk_bf16_f32.
// grid (64 t-tiles, 32 bh), block 256.
// ---------------------------------------------------------------------------
__global__ __launch_bounds__(256) void k_attn(const unsigned short* __restrict__ qt,
                                              const unsigned short* __restrict__ kt,
                                              const unsigned short* __restrict__ vb,
                                              const unsigned short* __restrict__ ones,
                                              unsigned short* __restrict__ abuf) {
    int wv = threadIdx.x >> 6;          // split index 0..3
    int lane = threadIdx.x & 63;
    int hi = lane >> 5, tlo = lane & 31;
    int bh = blockIdx.y;
    int t0 = blockIdx.x * 32;

    __shared__ float lds_d2[3][32][33];

    const unsigned short* qp = qt + (size_t)bh * (LL * 16);
    const unsigned short* kpt = kt + (size_t)bh * (LL * 16)
                                + (size_t)(wv * 512 + tlo) * 16 + 8 * hi;
    const unsigned short* vpt = (tlo < 16)
        ? vb + (size_t)bh * (16 * LL) + (size_t)tlo * LL + wv * 512 + 8 * hi
        : ones + wv * 512 + 8 * hi;      // lanes 16-31 feed 1.0 -> lsum cols

    short8 qf = *(const short8*)(qp + (size_t)(t0 + tlo) * 16 + 8 * hi);

    f32x16 d2 = {};
    const f32x16 z = {};

    short8 kf  = *(const short8*)kpt;
    short8 vf0 = *(const short8*)vpt;
    short8 vf1 = *(const short8*)(vpt + 16);

#pragma unroll 4
    for (int it = 0; it < 16; ++it) {
        kpt += 32 * 16;
        vpt += 32;
        short8 kn  = *(const short8*)kpt;       // prefetch next tile
        short8 vn0 = *(const short8*)vpt;
        short8 vn1 = *(const short8*)(vpt + 16);

        f32x16 d1 = __builtin_amdgcn_mfma_f32_32x32x16_bf16(kf, qf, z, 0, 0, 0);

        float p[16];
#pragma unroll
        for (int r = 0; r < 16; r++) p[r] = exp2_fast(d1[r]);

        uint32_t pk[8];
#pragma unroll
        for (int i = 0; i < 8; i++) pk[i] = cvtpk(p[2 * i], p[2 * i + 1]);

        permswap(pk[0], pk[2]);
        permswap(pk[1], pk[3]);
        permswap(pk[4], pk[6]);
        permswap(pk[5], pk[7]);
        union { uint32_t u[4]; short8 s; } A1, A2;
        A1.u[0] = pk[0]; A1.u[1] = pk[1]; A1.u[2] = pk[2]; A1.u[3] = pk[3];
        A2.u[0] = pk[4]; A2.u[1] = pk[5]; A2.u[2] = pk[6]; A2.u[3] = pk[7];

        d2 = __builtin_amdgcn_mfma_f32_32x32x16_bf16(A1.s, vf0, d2, 0, 0, 0);
        d2 = __builtin_amdgcn_mfma_f32_32x32x16_bf16(A2.s, vf1, d2, 0, 0, 0);

        kf = kn; vf0 = vn0; vf1 = vn1;
    }

    if (wv > 0) {
        int w = wv - 1;
#pragma unroll
        for (int r = 0; r < 16; r++) {
            int row = (r & 3) + 8 * (r >> 2) + 4 * hi;
            lds_d2[w][row][tlo] = d2[r];   // O cols 0-15, lsum cols 16-31
        }
    }
    __syncthreads();
    if (wv == 0) {
        unsigned short* op = abuf + ((size_t)bh * 16 + tlo) * LL + t0;
        float v[16];
#pragma unroll
        for (int r = 0; r < 16; r++) {
            int row = (r & 3) + 8 * (r >> 2) + 4 * hi;
            float osum = d2[r] + lds_d2[0][row][tlo]
                       + lds_d2[1][row][tlo] + lds_d2[2][row][tlo];
            float rv = rcp_fast(osum);           // meaningful on lanes 16-31
            float rl = __shfl_xor(rv, 16, 64);   // O-lanes fetch rcp(lsum)
            v[r] = osum * rl;
        }
        if (tlo < 16) {
#pragma unroll
            for (int g = 0; g < 4; g++) {
                uint2 pkv = make_uint2(cvtpk(v[4 * g], v[4 * g + 1]),
                                       cvtpk(v[4 * g + 2], v[4 * g + 3]));
                *(uint2*)(op + 8 * g + 4 * hi) = pkv;
            }
        }
    }
}

// ---------------------------------------------------------------------------
// Kernel 4: proj conv1x1 as bf16 MFMA GEMM + bias + fp32 residual.
// grid (32 lt, 8 b), block 256 (4 waves).
// ---------------------------------------------------------------------------
__global__ __launch_bounds__(256) void k_proj(const float* __restrict__ x,
                                              const unsigned short* __restrict__ abuf,
                                              const float* __restrict__ pw,
                                              const float* __restrict__ pb,
                                              float* __restrict__ out) {
    int lt = blockIdx.x;   // 0..31
    int b  = blockIdx.y;   // 0..7
    int tid = threadIdx.x;
    int l0 = lt * 64;
    __shared__ unsigned short as_[64 * 64];  // [l][c] swizzled
    __shared__ unsigned short ws[64 * 64];   // [o][c] swizzled

    {
        int cq = tid >> 4, t4 = tid & 15, c0 = cq * 4;
        uint2 ld0 = *(const uint2*)(abuf + (size_t)(b * 64 + c0)     * LL + l0 + t4 * 4);
        uint2 ld1 = *(const uint2*)(abuf + (size_t)(b * 64 + c0 + 1) * LL + l0 + t4 * 4);
        uint2 ld2 = *(const uint2*)(abuf + (size_t)(b * 64 + c0 + 2) * LL + l0 + t4 * 4);
        uint2 ld3 = *(const uint2*)(abuf + (size_t)(b * 64 + c0 + 3) * LL + l0 + t4 * 4);
        const unsigned short* s0 = (const unsigned short*)&ld0;
        const unsigned short* s1 = (const unsigned short*)&ld1;
        const unsigned short* s2 = (const unsigned short*)&ld2;
        const unsigned short* s3 = (const unsigned short*)&ld3;
#pragma unroll
        for (int j = 0; j < 4; j++) {
            int l = t4 * 4 + j;
            uint32_t lo = (uint32_t)s0[j] | ((uint32_t)s1[j] << 16);
            uint32_t hw = (uint32_t)s2[j] | ((uint32_t)s3[j] << 16);
            *(uint2*)&as_[l * 64 + (c0 ^ ((l & 7) << 3))] = make_uint2(lo, hw);
        }
    }
#pragma unroll
    for (int k = 0; k < 4; k++) {
        int chunk = tid + k * 256;
        int o = chunk >> 4, c4 = chunk & 15;
        f32x4 wv4 = *(const f32x4*)(pw + (size_t)o * 64 + c4 * 4);
        uint2 pw2 = make_uint2(cvtpk(wv4[0], wv4[1]), cvtpk(wv4[2], wv4[3]));
        *(uint2*)&ws[o * 64 + ((c4 * 4) ^ ((o & 7) << 3))] = pw2;
    }
    __syncthreads();

    int wv_ = tid >> 6, lane = tid & 63, hi = lane >> 5, tl = lane & 31;
    int o0 = (wv_ & 1) * 32, lw = (wv_ >> 1) * 32;
    int arow = o0 + tl, brow = lw + tl;
    f32x16 acc = {};
#pragma unroll
    for (int kk = 0; kk < 4; kk++) {
        int cb = kk * 16 + hi * 8;
        short8 af = *(const short8*)&ws[arow * 64 + (cb ^ ((arow & 7) << 3))];
        short8 bf = *(const short8*)&as_[brow * 64 + (cb ^ ((brow & 7) << 3))];
        acc = __builtin_amdgcn_mfma_f32_32x32x16_bf16(af, bf, acc, 0, 0, 0);
    }

    int l = l0 + lw + tl;
#pragma unroll
    for (int r = 0; r < 16; r++) {
        int o = o0 + (r & 3) + 8 * (r >> 2) + 4 * hi;
        size_t idx = (size_t)(b * 64 + o) * LL + l;
        out[idx] = x[idx] + acc[r] + pb[o];
    }
}

// ---------------------------------------------------------------------------
extern "C" void kernel_launch(void* const* d_in, const int* in_sizes, int n_in,
                              void* d_out, int out_size, void* d_ws, size_t ws_size,
                              hipStream_t stream) {
    const float* x   = (const float*)d_in[0];
    const float* gnw = (const float*)d_in[1];
    const float* gnb = (const float*)d_in[2];
    const float* qw  = (const float*)d_in[3];
    const float* qb  = (const float*)d_in[4];
    const float* pw  = (const float*)d_in[5];
    const float* pb  = (const float*)d_in[6];
    float* out = (float*)d_out;

    float* wsf   = (float*)d_ws;
    float* stats = wsf;                                  // 256 floats (partials)
    unsigned short* qt = (unsigned short*)(wsf + 256);   // 32*2048*16 bf16
    unsigned short* kt = qt + (size_t)32 * LL * 16;
    unsigned short* vb = kt + (size_t)32 * LL * 16;
    unsigned short* abuf = vb + (size_t)32 * LL * 16;    // 8*64*2048 bf16
    unsigned short* ones = abuf + (size_t)8 * 64 * LL;   // 4096 bf16 of 1.0

    hipLaunchKernelGGL(k_gnstats, dim3(128), dim3(256), 0, stream, x, stats, ones);
    hipLaunchKernelGGL(k_qkv, dim3(32, 3, 8), dim3(256), 0, stream,
                       x, gnw, gnb, qw, qb, stats, qt, kt, vb);
    hipLaunchKernelGGL(k_attn, dim3(64, 32), dim3(256), 0, stream,
                       qt, kt, vb, ones, abuf);
    hipLaunchKernelGGL(k_proj, dim3(32, 8), dim3(256), 0, stream,
                       x, abuf, pw, pb, out);
}